// Round 1
// baseline (976.999 us; speedup 1.0000x reference)
//
#include <hip/hip_runtime.h>
#include <cstdint>

#define CDIV(a, b) (((a) + (b) - 1) / (b))

// ---------------- degree / dis ----------------
__global__ void k_deg(const int* __restrict__ dst, int E, int* __restrict__ degc) {
    int e = blockIdx.x * blockDim.x + threadIdx.x;
    if (e < E) atomicAdd(&degc[dst[e]], 1);
}

__global__ void k_dis(const int* __restrict__ degc, int N, float* __restrict__ dis) {
    int i = blockIdx.x * blockDim.x + threadIdx.x;
    if (i < N) dis[i] = rsqrtf((float)degc[i] + 1.0f);
}

// ---------------- exclusive scan over degc -> row_ptr ----------------
// chunk = 1024 elements per block (256 threads x 4)
__global__ void k_scan_partial(const int* __restrict__ degc, int N, int* __restrict__ csum) {
    __shared__ int sm[256];
    int t = threadIdx.x;
    int idx = blockIdx.x * 1024 + t * 4;
    int s = 0;
#pragma unroll
    for (int j = 0; j < 4; ++j)
        if (idx + j < N) s += degc[idx + j];
    sm[t] = s;
    __syncthreads();
    for (int off = 128; off > 0; off >>= 1) {
        if (t < off) sm[t] += sm[t + off];
        __syncthreads();
    }
    if (t == 0) csum[blockIdx.x] = sm[0];
}

__global__ void k_scan_chunks(const int* __restrict__ csum, int nch, int* __restrict__ coff,
                              int* __restrict__ row_ptr, int N, int E) {
    if (threadIdx.x == 0 && blockIdx.x == 0) {
        int run = 0;
        for (int i = 0; i < nch; ++i) { coff[i] = run; run += csum[i]; }
        row_ptr[N] = E;
    }
}

__global__ void k_scan_final(const int* __restrict__ degc, int N, const int* __restrict__ coff,
                             int* __restrict__ row_ptr) {
    __shared__ int sm[256];
    int t = threadIdx.x;
    int idx = blockIdx.x * 1024 + t * 4;
    int v[4];
    int s = 0;
#pragma unroll
    for (int j = 0; j < 4; ++j) {
        v[j] = (idx + j < N) ? degc[idx + j] : 0;
        s += v[j];
    }
    sm[t] = s;
    __syncthreads();
    for (int off = 1; off < 256; off <<= 1) {
        int x = (t >= off) ? sm[t - off] : 0;
        __syncthreads();
        sm[t] += x;
        __syncthreads();
    }
    int excl = sm[t] - s + coff[blockIdx.x];
#pragma unroll
    for (int j = 0; j < 4; ++j) {
        if (idx + j < N) { row_ptr[idx + j] = excl; excl += v[j]; }
    }
}

// ---------------- CSR fill ----------------
__global__ void k_fill(const int* __restrict__ src, const int* __restrict__ dst, int E,
                       const int* __restrict__ row_ptr, int* __restrict__ fill,
                       const float* __restrict__ dis, int* __restrict__ esrc,
                       float* __restrict__ ecoef) {
    int e = blockIdx.x * blockDim.x + threadIdx.x;
    if (e >= E) return;
    int d = dst[e], s = src[e];
    int pos = row_ptr[d] + atomicAdd(&fill[d], 1);
    esrc[pos] = s;
    ecoef[pos] = dis[s] * dis[d];
}

// ---------------- aggregation: out[i] = dis_i^2 * x[i] + sum_e c_e * x[src_e]
// one wave per node; C = 128 (V=2) or 256 (V=4) columns
template <int C>
__global__ __launch_bounds__(256) void k_agg(const float* __restrict__ x,
                                             const float* __restrict__ dis,
                                             const int* __restrict__ row_ptr,
                                             const int* __restrict__ esrc,
                                             const float* __restrict__ ecoef, int N,
                                             float* __restrict__ out) {
    constexpr int V = C / 64;
    int wave = (blockIdx.x * blockDim.x + threadIdx.x) >> 6;
    int lane = threadIdx.x & 63;
    if (wave >= N) return;
    const int i = wave;
    float di = dis[i];
    float dd = di * di;
    float acc[V];
    {
        const float* xr = x + (size_t)i * C + lane * V;
        if constexpr (V == 4) {
            float4 v = *reinterpret_cast<const float4*>(xr);
            acc[0] = dd * v.x; acc[1] = dd * v.y; acc[2] = dd * v.z; acc[3] = dd * v.w;
        } else {
            float2 v = *reinterpret_cast<const float2*>(xr);
            acc[0] = dd * v.x; acc[1] = dd * v.y;
        }
    }
    int p0 = row_ptr[i], p1 = row_ptr[i + 1];
    for (int p = p0; p < p1; ++p) {
        int s = esrc[p];
        float c = ecoef[p];
        const float* xs = x + (size_t)s * C + lane * V;
        if constexpr (V == 4) {
            float4 v = *reinterpret_cast<const float4*>(xs);
            acc[0] += c * v.x; acc[1] += c * v.y; acc[2] += c * v.z; acc[3] += c * v.w;
        } else {
            float2 v = *reinterpret_cast<const float2*>(xs);
            acc[0] += c * v.x; acc[1] += c * v.y;
        }
    }
    float* o = out + (size_t)i * C + lane * V;
    if constexpr (V == 4) {
        *reinterpret_cast<float4*>(o) = make_float4(acc[0], acc[1], acc[2], acc[3]);
    } else {
        *reinterpret_cast<float2*>(o) = make_float2(acc[0], acc[1]);
    }
}

// ---------------- f32 GEMM: C[M,256] = relu(A[M,K] @ B[K,256] + bias) ----------------
// 64x64 tile per block, 256 threads, 4x4 per thread
template <int K>
__global__ __launch_bounds__(256) void k_gemm(const float* __restrict__ A,
                                              const float* __restrict__ B,
                                              const float* __restrict__ bias, int M,
                                              float* __restrict__ C, int do_relu) {
    __shared__ float As[16][64];
    __shared__ float Bs[16][64];
    const int t = threadIdx.x;
    const int tm = (t >> 4) << 2;  // 0..60
    const int tn = (t & 15) << 2;  // 0..60
    const int bm = blockIdx.x * 64;
    const int bn = blockIdx.y * 64;
    float acc[4][4] = {};
    const int la_r = t >> 2;        // 0..63
    const int la_c = (t & 3) << 2;  // 0,4,8,12
    const int lb_r = t >> 4;        // 0..15
    const int lb_c = (t & 15) << 2; // 0..60
    for (int k0 = 0; k0 < K; k0 += 16) {
        float4 av = make_float4(0.f, 0.f, 0.f, 0.f);
        int ar = bm + la_r;
        if (ar < M) av = *reinterpret_cast<const float4*>(&A[(size_t)ar * K + k0 + la_c]);
        As[la_c + 0][la_r] = av.x;
        As[la_c + 1][la_r] = av.y;
        As[la_c + 2][la_r] = av.z;
        As[la_c + 3][la_r] = av.w;
        float4 bv = *reinterpret_cast<const float4*>(&B[(size_t)(k0 + lb_r) * 256 + bn + lb_c]);
        *reinterpret_cast<float4*>(&Bs[lb_r][lb_c]) = bv;
        __syncthreads();
#pragma unroll
        for (int kk = 0; kk < 16; ++kk) {
            float4 a = *reinterpret_cast<const float4*>(&As[kk][tm]);
            float4 b = *reinterpret_cast<const float4*>(&Bs[kk][tn]);
            acc[0][0] += a.x * b.x; acc[0][1] += a.x * b.y; acc[0][2] += a.x * b.z; acc[0][3] += a.x * b.w;
            acc[1][0] += a.y * b.x; acc[1][1] += a.y * b.y; acc[1][2] += a.y * b.z; acc[1][3] += a.y * b.w;
            acc[2][0] += a.z * b.x; acc[2][1] += a.z * b.y; acc[2][2] += a.z * b.z; acc[2][3] += a.z * b.w;
            acc[3][0] += a.w * b.x; acc[3][1] += a.w * b.y; acc[3][2] += a.w * b.z; acc[3][3] += a.w * b.w;
        }
        __syncthreads();
    }
    float4 bia = *reinterpret_cast<const float4*>(&bias[bn + tn]);
#pragma unroll
    for (int i = 0; i < 4; ++i) {
        int r = bm + tm + i;
        if (r < M) {
            float4 o;
            o.x = acc[i][0] + bia.x;
            o.y = acc[i][1] + bia.y;
            o.z = acc[i][2] + bia.z;
            o.w = acc[i][3] + bia.w;
            if (do_relu) {
                o.x = fmaxf(o.x, 0.f); o.y = fmaxf(o.y, 0.f);
                o.z = fmaxf(o.z, 0.f); o.w = fmaxf(o.w, 0.f);
            }
            *reinterpret_cast<float4*>(&C[(size_t)r * 256 + bn + tn]) = o;
        }
    }
}

// ---------------- pooling ----------------
__global__ void k_bounds(const int* __restrict__ batch, int N, int G, int* __restrict__ bstart) {
    int g = blockIdx.x * blockDim.x + threadIdx.x;
    if (g > G) return;
    int lo = 0, hi = N;
    while (lo < hi) {
        int mid = (lo + hi) >> 1;
        if (batch[mid] < g) lo = mid + 1; else hi = mid;
    }
    bstart[g] = lo;
}

__global__ __launch_bounds__(256) void k_pool(const float* __restrict__ h,
                                              const int* __restrict__ bstart,
                                              float* __restrict__ gfeat) {
    int g = blockIdx.x;
    int t = threadIdx.x;
    int s = bstart[g], e = bstart[g + 1];
    float sum = 0.f, mx = -INFINITY;
    for (int i = s; i < e; ++i) {
        float v = h[(size_t)i * 256 + t];
        sum += v;
        mx = fmaxf(mx, v);
    }
    int cnt = e - s;
    float mean = sum / fmaxf((float)cnt, 1.0f);
    if (cnt == 0) { mean = 0.f; mx = 0.f; }
    gfeat[g * 512 + t] = mean;
    gfeat[g * 512 + 256 + t] = mx;
}

// ---------------- MLP: out[g, j] = act(b[j] + sum_k in[g,k] W[k,j]) ----------------
__global__ void k_mlp(const float* __restrict__ in, const float* __restrict__ W,
                      const float* __restrict__ b, float* __restrict__ out, int Kdim, int Ndim,
                      int do_relu) {
    extern __shared__ float row[];
    int g = blockIdx.x, t = threadIdx.x;
    for (int k = t; k < Kdim; k += blockDim.x) row[k] = in[(size_t)g * Kdim + k];
    __syncthreads();
    if (t < Ndim) {
        float acc = b[t];
        for (int k = 0; k < Kdim; ++k) acc += row[k] * W[(size_t)k * Ndim + t];
        if (do_relu) acc = fmaxf(acc, 0.f);
        out[(size_t)g * Ndim + t] = acc;
    }
}

extern "C" void kernel_launch(void* const* d_in, const int* in_sizes, int n_in, void* d_out,
                              int out_size, void* d_ws, size_t ws_size, hipStream_t stream) {
    const float* x = (const float*)d_in[0];
    const int* eidx = (const int*)d_in[1];
    const int* batch = (const int*)d_in[2];
    const float* W1 = (const float*)d_in[3];
    const float* b1 = (const float*)d_in[4];
    const float* W2 = (const float*)d_in[5];
    const float* b2 = (const float*)d_in[6];
    const float* W3 = (const float*)d_in[7];
    const float* b3 = (const float*)d_in[8];
    const float* Wc1 = (const float*)d_in[9];
    const float* bc1 = (const float*)d_in[10];
    const float* Wc2 = (const float*)d_in[11];
    const float* bc2 = (const float*)d_in[12];
    const float* Wc3 = (const float*)d_in[13];
    const float* bc3 = (const float*)d_in[14];
    float* out = (float*)d_out;

    const int N = in_sizes[2];
    const int E = in_sizes[1] / 2;
    const int G = out_size / 5;
    const int* src = eidx;
    const int* dst = eidx + E;

    // workspace layout
    char* p = (char*)d_ws;
    auto alloc = [&](size_t bytes) {
        void* r = (void*)p;
        p += (bytes + 255) & ~(size_t)255;
        return r;
    };
    float* dis = (float*)alloc((size_t)N * 4);
    int* degc = (int*)alloc((size_t)N * 4);
    int* row_ptr = (int*)alloc((size_t)(N + 1) * 4);
    int* fill = (int*)alloc((size_t)N * 4);
    const int nch = CDIV(N, 1024);
    int* csum = (int*)alloc((size_t)nch * 4);
    int* coff = (int*)alloc((size_t)nch * 4);
    int* bstart = (int*)alloc((size_t)(G + 1) * 4);
    int* esrc = (int*)alloc((size_t)E * 4);
    float* ecoef = (float*)alloc((size_t)E * 4);
    float* gfeat = (float*)alloc((size_t)G * 512 * 4);
    float* g1 = (float*)alloc((size_t)G * 512 * 4);
    float* g2 = (float*)alloc((size_t)G * 256 * 4);
    float* buf0 = (float*)alloc((size_t)N * 256 * 4);
    float* buf1 = (float*)alloc((size_t)N * 256 * 4);
    (void)ws_size;

    hipMemsetAsync(degc, 0, (size_t)N * 4, stream);
    hipMemsetAsync(fill, 0, (size_t)N * 4, stream);

    k_deg<<<CDIV(E, 256), 256, 0, stream>>>(dst, E, degc);
    k_dis<<<CDIV(N, 256), 256, 0, stream>>>(degc, N, dis);
    k_scan_partial<<<nch, 256, 0, stream>>>(degc, N, csum);
    k_scan_chunks<<<1, 64, 0, stream>>>(csum, nch, coff, row_ptr, N, E);
    k_scan_final<<<nch, 256, 0, stream>>>(degc, N, coff, row_ptr);
    k_fill<<<CDIV(E, 256), 256, 0, stream>>>(src, dst, E, row_ptr, fill, dis, esrc, ecoef);

    // layer 1: aggregate x (128 cols) then GEMM K=128
    k_agg<128><<<CDIV(N * 64, 256), 256, 0, stream>>>(x, dis, row_ptr, esrc, ecoef, N, buf1);
    {
        dim3 grid(CDIV(N, 64), 4);
        k_gemm<128><<<grid, 256, 0, stream>>>(buf1, W1, b1, N, buf0, 1);
    }
    // layer 2
    k_agg<256><<<CDIV(N * 64, 256), 256, 0, stream>>>(buf0, dis, row_ptr, esrc, ecoef, N, buf1);
    {
        dim3 grid(CDIV(N, 64), 4);
        k_gemm<256><<<grid, 256, 0, stream>>>(buf1, W2, b2, N, buf0, 1);
    }
    // layer 3
    k_agg<256><<<CDIV(N * 64, 256), 256, 0, stream>>>(buf0, dis, row_ptr, esrc, ecoef, N, buf1);
    {
        dim3 grid(CDIV(N, 64), 4);
        k_gemm<256><<<grid, 256, 0, stream>>>(buf1, W3, b3, N, buf0, 1);
    }

    // pooling
    k_bounds<<<1, 128, 0, stream>>>(batch, N, G, bstart);
    k_pool<<<G, 256, 0, stream>>>(buf0, bstart, gfeat);

    // MLP head
    k_mlp<<<G, 512, 512 * 4, stream>>>(gfeat, Wc1, bc1, g1, 512, 512, 1);
    k_mlp<<<G, 256, 512 * 4, stream>>>(g1, Wc2, bc2, g2, 512, 256, 1);
    k_mlp<<<G, 64, 256 * 4, stream>>>(g2, Wc3, bc3, out, 256, 5, 0);
}

// Round 2
// 782.311 us; speedup vs baseline: 1.2489x; 1.2489x over previous
//
#include <hip/hip_runtime.h>
#include <cstdint>

#define CDIV(a, b) (((a) + (b) - 1) / (b))

// ---------------- degree / dis ----------------
__global__ void k_deg(const int* __restrict__ dst, int E, int* __restrict__ degc) {
    int e = blockIdx.x * blockDim.x + threadIdx.x;
    if (e < E) atomicAdd(&degc[dst[e]], 1);
}

__global__ void k_dis(const int* __restrict__ degc, int N, float* __restrict__ dis) {
    int i = blockIdx.x * blockDim.x + threadIdx.x;
    if (i < N) dis[i] = rsqrtf((float)degc[i] + 1.0f);
}

// ---------------- exclusive scan over degc -> row_ptr ----------------
__global__ void k_scan_partial(const int* __restrict__ degc, int N, int* __restrict__ csum) {
    __shared__ int sm[256];
    int t = threadIdx.x;
    int idx = blockIdx.x * 1024 + t * 4;
    int s = 0;
#pragma unroll
    for (int j = 0; j < 4; ++j)
        if (idx + j < N) s += degc[idx + j];
    sm[t] = s;
    __syncthreads();
    for (int off = 128; off > 0; off >>= 1) {
        if (t < off) sm[t] += sm[t + off];
        __syncthreads();
    }
    if (t == 0) csum[blockIdx.x] = sm[0];
}

__global__ void k_scan_chunks(const int* __restrict__ csum, int nch, int* __restrict__ coff,
                              int* __restrict__ row_ptr, int N, int E) {
    if (threadIdx.x == 0 && blockIdx.x == 0) {
        int run = 0;
        for (int i = 0; i < nch; ++i) { coff[i] = run; run += csum[i]; }
        row_ptr[N] = E;
    }
}

__global__ void k_scan_final(const int* __restrict__ degc, int N, const int* __restrict__ coff,
                             int* __restrict__ row_ptr) {
    __shared__ int sm[256];
    int t = threadIdx.x;
    int idx = blockIdx.x * 1024 + t * 4;
    int v[4];
    int s = 0;
#pragma unroll
    for (int j = 0; j < 4; ++j) {
        v[j] = (idx + j < N) ? degc[idx + j] : 0;
        s += v[j];
    }
    sm[t] = s;
    __syncthreads();
    for (int off = 1; off < 256; off <<= 1) {
        int x = (t >= off) ? sm[t - off] : 0;
        __syncthreads();
        sm[t] += x;
        __syncthreads();
    }
    int excl = sm[t] - s + coff[blockIdx.x];
#pragma unroll
    for (int j = 0; j < 4; ++j) {
        if (idx + j < N) { row_ptr[idx + j] = excl; excl += v[j]; }
    }
}

// ---------------- CSR fill ----------------
__global__ void k_fill(const int* __restrict__ src, const int* __restrict__ dst, int E,
                       const int* __restrict__ row_ptr, int* __restrict__ fill,
                       const float* __restrict__ dis, int* __restrict__ esrc,
                       float* __restrict__ ecoef) {
    int e = blockIdx.x * blockDim.x + threadIdx.x;
    if (e >= E) return;
    int d = dst[e], s = src[e];
    int pos = row_ptr[d] + atomicAdd(&fill[d], 1);
    esrc[pos] = s;
    ecoef[pos] = dis[s] * dis[d];
}

// ---------------- aggregation ----------------
template <int C>
__global__ __launch_bounds__(256) void k_agg(const float* __restrict__ x,
                                             const float* __restrict__ dis,
                                             const int* __restrict__ row_ptr,
                                             const int* __restrict__ esrc,
                                             const float* __restrict__ ecoef, int N,
                                             float* __restrict__ out) {
    constexpr int V = C / 64;
    int wave = (blockIdx.x * blockDim.x + threadIdx.x) >> 6;
    int lane = threadIdx.x & 63;
    if (wave >= N) return;
    const int i = wave;
    float di = dis[i];
    float dd = di * di;
    float acc[V];
    {
        const float* xr = x + (size_t)i * C + lane * V;
        if constexpr (V == 4) {
            float4 v = *reinterpret_cast<const float4*>(xr);
            acc[0] = dd * v.x; acc[1] = dd * v.y; acc[2] = dd * v.z; acc[3] = dd * v.w;
        } else {
            float2 v = *reinterpret_cast<const float2*>(xr);
            acc[0] = dd * v.x; acc[1] = dd * v.y;
        }
    }
    int p0 = row_ptr[i], p1 = row_ptr[i + 1];
    for (int p = p0; p < p1; ++p) {
        int s = esrc[p];
        float c = ecoef[p];
        const float* xs = x + (size_t)s * C + lane * V;
        if constexpr (V == 4) {
            float4 v = *reinterpret_cast<const float4*>(xs);
            acc[0] += c * v.x; acc[1] += c * v.y; acc[2] += c * v.z; acc[3] += c * v.w;
        } else {
            float2 v = *reinterpret_cast<const float2*>(xs);
            acc[0] += c * v.x; acc[1] += c * v.y;
        }
    }
    float* o = out + (size_t)i * C + lane * V;
    if constexpr (V == 4) {
        *reinterpret_cast<float4*>(o) = make_float4(acc[0], acc[1], acc[2], acc[3]);
    } else {
        *reinterpret_cast<float2*>(o) = make_float2(acc[0], acc[1]);
    }
}

// ---------------- f32 GEMM ----------------
template <int K>
__global__ __launch_bounds__(256) void k_gemm(const float* __restrict__ A,
                                              const float* __restrict__ B,
                                              const float* __restrict__ bias, int M,
                                              float* __restrict__ C, int do_relu) {
    __shared__ float As[16][64];
    __shared__ float Bs[16][64];
    const int t = threadIdx.x;
    const int tm = (t >> 4) << 2;
    const int tn = (t & 15) << 2;
    const int bm = blockIdx.x * 64;
    const int bn = blockIdx.y * 64;
    float acc[4][4] = {};
    const int la_r = t >> 2;
    const int la_c = (t & 3) << 2;
    const int lb_r = t >> 4;
    const int lb_c = (t & 15) << 2;
    for (int k0 = 0; k0 < K; k0 += 16) {
        float4 av = make_float4(0.f, 0.f, 0.f, 0.f);
        int ar = bm + la_r;
        if (ar < M) av = *reinterpret_cast<const float4*>(&A[(size_t)ar * K + k0 + la_c]);
        As[la_c + 0][la_r] = av.x;
        As[la_c + 1][la_r] = av.y;
        As[la_c + 2][la_r] = av.z;
        As[la_c + 3][la_r] = av.w;
        float4 bv = *reinterpret_cast<const float4*>(&B[(size_t)(k0 + lb_r) * 256 + bn + lb_c]);
        *reinterpret_cast<float4*>(&Bs[lb_r][lb_c]) = bv;
        __syncthreads();
#pragma unroll
        for (int kk = 0; kk < 16; ++kk) {
            float4 a = *reinterpret_cast<const float4*>(&As[kk][tm]);
            float4 b = *reinterpret_cast<const float4*>(&Bs[kk][tn]);
            acc[0][0] += a.x * b.x; acc[0][1] += a.x * b.y; acc[0][2] += a.x * b.z; acc[0][3] += a.x * b.w;
            acc[1][0] += a.y * b.x; acc[1][1] += a.y * b.y; acc[1][2] += a.y * b.z; acc[1][3] += a.y * b.w;
            acc[2][0] += a.z * b.x; acc[2][1] += a.z * b.y; acc[2][2] += a.z * b.z; acc[2][3] += a.z * b.w;
            acc[3][0] += a.w * b.x; acc[3][1] += a.w * b.y; acc[3][2] += a.w * b.z; acc[3][3] += a.w * b.w;
        }
        __syncthreads();
    }
    float4 bia = *reinterpret_cast<const float4*>(&bias[bn + tn]);
#pragma unroll
    for (int i = 0; i < 4; ++i) {
        int r = bm + tm + i;
        if (r < M) {
            float4 o;
            o.x = acc[i][0] + bia.x;
            o.y = acc[i][1] + bia.y;
            o.z = acc[i][2] + bia.z;
            o.w = acc[i][3] + bia.w;
            if (do_relu) {
                o.x = fmaxf(o.x, 0.f); o.y = fmaxf(o.y, 0.f);
                o.z = fmaxf(o.z, 0.f); o.w = fmaxf(o.w, 0.f);
            }
            *reinterpret_cast<float4*>(&C[(size_t)r * 256 + bn + tn]) = o;
        }
    }
}

// ---------------- pooling ----------------
__global__ void k_bounds(const int* __restrict__ batch, int N, int G, int* __restrict__ bstart) {
    int g = blockIdx.x * blockDim.x + threadIdx.x;
    if (g > G) return;
    int lo = 0, hi = N;
    while (lo < hi) {
        int mid = (lo + hi) >> 1;
        if (batch[mid] < g) lo = mid + 1; else hi = mid;
    }
    bstart[g] = lo;
}

// chunked pooling: grid = CDIV(N, ROWS) blocks x 256 threads (one per column).
// Each block reduces its rows in registers per graph-run (batch sorted), then
// flushes one atomicAdd + one int atomicMax per column per run. Values are
// post-ReLU (>=0) so int compare == float compare and init 0 is the identity.
#define POOL_ROWS 32
__global__ __launch_bounds__(256) void k_pool_partial(const float* __restrict__ h,
                                                      const int* __restrict__ batch, int N,
                                                      float* __restrict__ sumbuf,
                                                      int* __restrict__ maxbuf) {
    int t = threadIdx.x;
    int base = blockIdx.x * POOL_ROWS;
    int end = min(base + POOL_ROWS, N);
    float s = 0.f, m = 0.f;
    int gcur = batch[base];
    for (int i = base; i < end; ++i) {
        int g = batch[i];
        if (g != gcur) {
            atomicAdd(&sumbuf[gcur * 256 + t], s);
            atomicMax(&maxbuf[gcur * 256 + t], __float_as_int(m));
            s = 0.f; m = 0.f; gcur = g;
        }
        float v = h[(size_t)i * 256 + t];
        s += v;
        m = fmaxf(m, v);
    }
    atomicAdd(&sumbuf[gcur * 256 + t], s);
    atomicMax(&maxbuf[gcur * 256 + t], __float_as_int(m));
}

__global__ __launch_bounds__(256) void k_pool_final(const float* __restrict__ sumbuf,
                                                    const int* __restrict__ maxbuf,
                                                    const int* __restrict__ bstart,
                                                    float* __restrict__ gfeat) {
    int g = blockIdx.x;
    int t = threadIdx.x;
    int cnt = bstart[g + 1] - bstart[g];
    float mean = sumbuf[g * 256 + t] / fmaxf((float)cnt, 1.0f);
    float mx = __int_as_float(maxbuf[g * 256 + t]);
    if (cnt == 0) { mean = 0.f; mx = 0.f; }
    gfeat[g * 512 + t] = mean;
    gfeat[g * 512 + 256 + t] = mx;
}

// ---------------- MLP ----------------
__global__ void k_mlp(const float* __restrict__ in, const float* __restrict__ W,
                      const float* __restrict__ b, float* __restrict__ out, int Kdim, int Ndim,
                      int do_relu) {
    extern __shared__ float row[];
    int g = blockIdx.x, t = threadIdx.x;
    for (int k = t; k < Kdim; k += blockDim.x) row[k] = in[(size_t)g * Kdim + k];
    __syncthreads();
    if (t < Ndim) {
        float acc = b[t];
        for (int k = 0; k < Kdim; ++k) acc += row[k] * W[(size_t)k * Ndim + t];
        if (do_relu) acc = fmaxf(acc, 0.f);
        out[(size_t)g * Ndim + t] = acc;
    }
}

extern "C" void kernel_launch(void* const* d_in, const int* in_sizes, int n_in, void* d_out,
                              int out_size, void* d_ws, size_t ws_size, hipStream_t stream) {
    const float* x = (const float*)d_in[0];
    const int* eidx = (const int*)d_in[1];
    const int* batch = (const int*)d_in[2];
    const float* W1 = (const float*)d_in[3];
    const float* b1 = (const float*)d_in[4];
    const float* W2 = (const float*)d_in[5];
    const float* b2 = (const float*)d_in[6];
    const float* W3 = (const float*)d_in[7];
    const float* b3 = (const float*)d_in[8];
    const float* Wc1 = (const float*)d_in[9];
    const float* bc1 = (const float*)d_in[10];
    const float* Wc2 = (const float*)d_in[11];
    const float* bc2 = (const float*)d_in[12];
    const float* Wc3 = (const float*)d_in[13];
    const float* bc3 = (const float*)d_in[14];
    float* out = (float*)d_out;

    const int N = in_sizes[2];
    const int E = in_sizes[1] / 2;
    const int G = out_size / 5;
    const int* src = eidx;
    const int* dst = eidx + E;

    char* p = (char*)d_ws;
    auto alloc = [&](size_t bytes) {
        void* r = (void*)p;
        p += (bytes + 255) & ~(size_t)255;
        return r;
    };
    float* dis = (float*)alloc((size_t)N * 4);
    int* degc = (int*)alloc((size_t)N * 4);
    int* row_ptr = (int*)alloc((size_t)(N + 1) * 4);
    int* fill = (int*)alloc((size_t)N * 4);
    const int nch = CDIV(N, 1024);
    int* csum = (int*)alloc((size_t)nch * 4);
    int* coff = (int*)alloc((size_t)nch * 4);
    int* bstart = (int*)alloc((size_t)(G + 1) * 4);
    int* esrc = (int*)alloc((size_t)E * 4);
    float* ecoef = (float*)alloc((size_t)E * 4);
    float* sumbuf = (float*)alloc((size_t)G * 256 * 4);
    int* maxbuf = (int*)alloc((size_t)G * 256 * 4);
    float* gfeat = (float*)alloc((size_t)G * 512 * 4);
    float* g1 = (float*)alloc((size_t)G * 512 * 4);
    float* g2 = (float*)alloc((size_t)G * 256 * 4);
    float* buf0 = (float*)alloc((size_t)N * 256 * 4);
    float* buf1 = (float*)alloc((size_t)N * 256 * 4);
    (void)ws_size;

    hipMemsetAsync(degc, 0, (size_t)N * 4, stream);
    hipMemsetAsync(fill, 0, (size_t)N * 4, stream);
    hipMemsetAsync(sumbuf, 0, (size_t)G * 256 * 4, stream);
    hipMemsetAsync(maxbuf, 0, (size_t)G * 256 * 4, stream);

    k_deg<<<CDIV(E, 256), 256, 0, stream>>>(dst, E, degc);
    k_dis<<<CDIV(N, 256), 256, 0, stream>>>(degc, N, dis);
    k_scan_partial<<<nch, 256, 0, stream>>>(degc, N, csum);
    k_scan_chunks<<<1, 64, 0, stream>>>(csum, nch, coff, row_ptr, N, E);
    k_scan_final<<<nch, 256, 0, stream>>>(degc, N, coff, row_ptr);
    k_fill<<<CDIV(E, 256), 256, 0, stream>>>(src, dst, E, row_ptr, fill, dis, esrc, ecoef);

    // layer 1: aggregate x (128 cols) then GEMM K=128
    k_agg<128><<<CDIV(N * 64, 256), 256, 0, stream>>>(x, dis, row_ptr, esrc, ecoef, N, buf1);
    {
        dim3 grid(CDIV(N, 64), 4);
        k_gemm<128><<<grid, 256, 0, stream>>>(buf1, W1, b1, N, buf0, 1);
    }
    // layer 2
    k_agg<256><<<CDIV(N * 64, 256), 256, 0, stream>>>(buf0, dis, row_ptr, esrc, ecoef, N, buf1);
    {
        dim3 grid(CDIV(N, 64), 4);
        k_gemm<256><<<grid, 256, 0, stream>>>(buf1, W2, b2, N, buf0, 1);
    }
    // layer 3
    k_agg<256><<<CDIV(N * 64, 256), 256, 0, stream>>>(buf0, dis, row_ptr, esrc, ecoef, N, buf1);
    {
        dim3 grid(CDIV(N, 64), 4);
        k_gemm<256><<<grid, 256, 0, stream>>>(buf1, W3, b3, N, buf0, 1);
    }

    // pooling
    k_bounds<<<1, 128, 0, stream>>>(batch, N, G, bstart);
    k_pool_partial<<<CDIV(N, POOL_ROWS), 256, 0, stream>>>(buf0, batch, N, sumbuf, maxbuf);
    k_pool_final<<<G, 256, 0, stream>>>(sumbuf, maxbuf, bstart, gfeat);

    // MLP head
    k_mlp<<<G, 512, 512 * 4, stream>>>(gfeat, Wc1, bc1, g1, 512, 512, 1);
    k_mlp<<<G, 256, 512 * 4, stream>>>(g1, Wc2, bc2, g2, 512, 256, 1);
    k_mlp<<<G, 64, 256 * 4, stream>>>(g2, Wc3, bc3, out, 256, 5, 0);
}

// Round 3
// 668.905 us; speedup vs baseline: 1.4606x; 1.1695x over previous
//
#include <hip/hip_runtime.h>
#include <cstdint>

#define CDIV(a, b) (((a) + (b) - 1) / (b))

typedef short bf16x8 __attribute__((ext_vector_type(8)));
typedef float f32x4 __attribute__((ext_vector_type(4)));

__device__ inline ushort f2bf_rn(float f) {
    uint32_t u = __float_as_uint(f);
    uint32_t rounding = 0x7FFF + ((u >> 16) & 1);
    return (ushort)((u + rounding) >> 16);
}
__device__ inline float bf2f(ushort h) { return __uint_as_float((uint32_t)h << 16); }

// ---------------- degree / dis ----------------
__global__ void k_deg(const int* __restrict__ dst, int E, int* __restrict__ degc) {
    int e = blockIdx.x * blockDim.x + threadIdx.x;
    if (e < E) atomicAdd(&degc[dst[e]], 1);
}

__global__ void k_dis(const int* __restrict__ degc, int N, float* __restrict__ dis) {
    int i = blockIdx.x * blockDim.x + threadIdx.x;
    if (i < N) dis[i] = rsqrtf((float)degc[i] + 1.0f);
}

// ---------------- exclusive scan over degc -> row_ptr ----------------
__global__ void k_scan_partial(const int* __restrict__ degc, int N, int* __restrict__ csum) {
    __shared__ int sm[256];
    int t = threadIdx.x;
    int idx = blockIdx.x * 1024 + t * 4;
    int s = 0;
#pragma unroll
    for (int j = 0; j < 4; ++j)
        if (idx + j < N) s += degc[idx + j];
    sm[t] = s;
    __syncthreads();
    for (int off = 128; off > 0; off >>= 1) {
        if (t < off) sm[t] += sm[t + off];
        __syncthreads();
    }
    if (t == 0) csum[blockIdx.x] = sm[0];
}

__global__ void k_scan_chunks(const int* __restrict__ csum, int nch, int* __restrict__ coff,
                              int* __restrict__ row_ptr, int N, int E) {
    if (threadIdx.x == 0 && blockIdx.x == 0) {
        int run = 0;
        for (int i = 0; i < nch; ++i) { coff[i] = run; run += csum[i]; }
        row_ptr[N] = E;
    }
}

__global__ void k_scan_final(const int* __restrict__ degc, int N, const int* __restrict__ coff,
                             int* __restrict__ row_ptr) {
    __shared__ int sm[256];
    int t = threadIdx.x;
    int idx = blockIdx.x * 1024 + t * 4;
    int v[4];
    int s = 0;
#pragma unroll
    for (int j = 0; j < 4; ++j) {
        v[j] = (idx + j < N) ? degc[idx + j] : 0;
        s += v[j];
    }
    sm[t] = s;
    __syncthreads();
    for (int off = 1; off < 256; off <<= 1) {
        int x = (t >= off) ? sm[t - off] : 0;
        __syncthreads();
        sm[t] += x;
        __syncthreads();
    }
    int excl = sm[t] - s + coff[blockIdx.x];
#pragma unroll
    for (int j = 0; j < 4; ++j) {
        if (idx + j < N) { row_ptr[idx + j] = excl; excl += v[j]; }
    }
}

// ---------------- CSR fill ----------------
__global__ void k_fill(const int* __restrict__ src, const int* __restrict__ dst, int E,
                       const int* __restrict__ row_ptr, int* __restrict__ fill,
                       const float* __restrict__ dis, int* __restrict__ esrc,
                       float* __restrict__ ecoef) {
    int e = blockIdx.x * blockDim.x + threadIdx.x;
    if (e >= E) return;
    int d = dst[e], s = src[e];
    int pos = row_ptr[d] + atomicAdd(&fill[d], 1);
    esrc[pos] = s;
    ecoef[pos] = dis[s] * dis[d];
}

// ---------------- aggregation (f32 gather, bf16 hi/lo split output) ----------------
// out[i] = dis_i^2 * x[i] + sum_e c_e * x[src_e]; one wave per node.
// Edge loop unrolled x4 so 4 row-gathers are in flight per wave (latency hiding).
// Epilogue splits f32 acc into bf16 hi + bf16 lo (hi+lo ~= f32 to 2^-16 rel)
// so the GEMM can run on the bf16 matrix cores without precision loss.
template <int C>
__global__ __launch_bounds__(256) void k_agg(const float* __restrict__ x,
                                             const float* __restrict__ dis,
                                             const int* __restrict__ row_ptr,
                                             const int* __restrict__ esrc,
                                             const float* __restrict__ ecoef, int N,
                                             ushort* __restrict__ ohi,
                                             ushort* __restrict__ olo) {
    constexpr int V = C / 64;
    int wave = (blockIdx.x * blockDim.x + threadIdx.x) >> 6;
    int lane = threadIdx.x & 63;
    if (wave >= N) return;
    const int i = wave;
    float di = dis[i];
    float dd = di * di;
    float acc[V];
    {
        const float* xr = x + (size_t)i * C + lane * V;
        if constexpr (V == 4) {
            float4 v = *reinterpret_cast<const float4*>(xr);
            acc[0] = dd * v.x; acc[1] = dd * v.y; acc[2] = dd * v.z; acc[3] = dd * v.w;
        } else {
            float2 v = *reinterpret_cast<const float2*>(xr);
            acc[0] = dd * v.x; acc[1] = dd * v.y;
        }
    }
    int p0 = row_ptr[i], p1 = row_ptr[i + 1];
    int p = p0;
    if constexpr (V == 4) {
        for (; p + 4 <= p1; p += 4) {
            int s0 = esrc[p], s1 = esrc[p + 1], s2 = esrc[p + 2], s3 = esrc[p + 3];
            float c0 = ecoef[p], c1 = ecoef[p + 1], c2 = ecoef[p + 2], c3 = ecoef[p + 3];
            float4 v0 = *reinterpret_cast<const float4*>(x + (size_t)s0 * C + lane * V);
            float4 v1 = *reinterpret_cast<const float4*>(x + (size_t)s1 * C + lane * V);
            float4 v2 = *reinterpret_cast<const float4*>(x + (size_t)s2 * C + lane * V);
            float4 v3 = *reinterpret_cast<const float4*>(x + (size_t)s3 * C + lane * V);
            acc[0] += c0 * v0.x; acc[1] += c0 * v0.y; acc[2] += c0 * v0.z; acc[3] += c0 * v0.w;
            acc[0] += c1 * v1.x; acc[1] += c1 * v1.y; acc[2] += c1 * v1.z; acc[3] += c1 * v1.w;
            acc[0] += c2 * v2.x; acc[1] += c2 * v2.y; acc[2] += c2 * v2.z; acc[3] += c2 * v2.w;
            acc[0] += c3 * v3.x; acc[1] += c3 * v3.y; acc[2] += c3 * v3.z; acc[3] += c3 * v3.w;
        }
        for (; p < p1; ++p) {
            int s = esrc[p];
            float c = ecoef[p];
            float4 v = *reinterpret_cast<const float4*>(x + (size_t)s * C + lane * V);
            acc[0] += c * v.x; acc[1] += c * v.y; acc[2] += c * v.z; acc[3] += c * v.w;
        }
    } else {
        for (; p + 4 <= p1; p += 4) {
            int s0 = esrc[p], s1 = esrc[p + 1], s2 = esrc[p + 2], s3 = esrc[p + 3];
            float c0 = ecoef[p], c1 = ecoef[p + 1], c2 = ecoef[p + 2], c3 = ecoef[p + 3];
            float2 v0 = *reinterpret_cast<const float2*>(x + (size_t)s0 * C + lane * V);
            float2 v1 = *reinterpret_cast<const float2*>(x + (size_t)s1 * C + lane * V);
            float2 v2 = *reinterpret_cast<const float2*>(x + (size_t)s2 * C + lane * V);
            float2 v3 = *reinterpret_cast<const float2*>(x + (size_t)s3 * C + lane * V);
            acc[0] += c0 * v0.x; acc[1] += c0 * v0.y;
            acc[0] += c1 * v1.x; acc[1] += c1 * v1.y;
            acc[0] += c2 * v2.x; acc[1] += c2 * v2.y;
            acc[0] += c3 * v3.x; acc[1] += c3 * v3.y;
        }
        for (; p < p1; ++p) {
            int s = esrc[p];
            float c = ecoef[p];
            float2 v = *reinterpret_cast<const float2*>(x + (size_t)s * C + lane * V);
            acc[0] += c * v.x; acc[1] += c * v.y;
        }
    }
    // split epilogue
    ushort hi[V], lo[V];
#pragma unroll
    for (int j = 0; j < V; ++j) {
        hi[j] = f2bf_rn(acc[j]);
        lo[j] = f2bf_rn(acc[j] - bf2f(hi[j]));
    }
    size_t ob = (size_t)i * C + lane * V;
    if constexpr (V == 4) {
        *reinterpret_cast<ushort4*>(ohi + ob) = make_ushort4(hi[0], hi[1], hi[2], hi[3]);
        *reinterpret_cast<ushort4*>(olo + ob) = make_ushort4(lo[0], lo[1], lo[2], lo[3]);
    } else {
        *reinterpret_cast<ushort2*>(ohi + ob) = make_ushort2(hi[0], hi[1]);
        *reinterpret_cast<ushort2*>(olo + ob) = make_ushort2(lo[0], lo[1]);
    }
}

// ---------------- W split + fragment swizzle ----------------
// Whi/Wlo laid out frag-linear: for k-step ks, n-frag nf, lane, j(0..7):
// element W[ks*32 + (lane>>4)*8 + j][nf*16 + (lane&15)]
__global__ void k_wsplit(const float* __restrict__ W, int K, ushort* __restrict__ Whi,
                         ushort* __restrict__ Wlo) {
    int idx = blockIdx.x * 256 + threadIdx.x;
    if (idx >= K * 256) return;
    int k = idx >> 8, n = idx & 255;
    float v = W[idx];
    ushort hi = f2bf_rn(v);
    ushort lo = f2bf_rn(v - bf2f(hi));
    int ks = k >> 5, r = k & 31;
    int lane = (r >> 3) * 16 + (n & 15);
    int j = r & 7;
    size_t d = (((size_t)ks * 16 + (n >> 4)) * 64 + lane) * 8 + j;
    Whi[d] = hi;
    Wlo[d] = lo;
}

// ---------------- split-bf16 MFMA GEMM: C[M,256] = relu(A @ W + bias) ----------------
// A = Ahi + Alo (bf16 pair), W = Whi + Wlo (bf16 pair, frag-swizzled).
// acc += Ahi*Whi + Ahi*Wlo + Alo*Whi  (lo*lo term ~2^-16, dropped).
// Block: 256 thr = 4 waves; tile BM=128 (wave owns 32 rows) x BN=128. No LDS;
// W frags (128 KB/layer) stay L2-resident.
template <int K>
__global__ __launch_bounds__(256) void k_gemm_bf16(const ushort* __restrict__ Ahi,
                                                   const ushort* __restrict__ Alo,
                                                   const ushort* __restrict__ Whi,
                                                   const ushort* __restrict__ Wlo,
                                                   const float* __restrict__ bias, int M,
                                                   float* __restrict__ C, int do_relu) {
    const int t = threadIdx.x;
    const int w = t >> 6, lane = t & 63;
    const int bm = blockIdx.x * 128;
    const int bn = blockIdx.y * 128;
    const int rw = bm + w * 32;

    f32x4 acc[2][8] = {};

    int row0 = min(rw + (lane & 15), M - 1);
    int row1 = min(rw + 16 + (lane & 15), M - 1);
    const int kbase = (lane >> 4) * 8;
    const ushort* pa0h = Ahi + (size_t)row0 * K + kbase;
    const ushort* pa0l = Alo + (size_t)row0 * K + kbase;
    const ushort* pa1h = Ahi + (size_t)row1 * K + kbase;
    const ushort* pa1l = Alo + (size_t)row1 * K + kbase;
    const int nf0 = bn >> 4;  // global n-frag base (0 or 8)

    for (int ks = 0; ks < K / 32; ++ks) {
        bf16x8 a0h = *reinterpret_cast<const bf16x8*>(pa0h + ks * 32);
        bf16x8 a0l = *reinterpret_cast<const bf16x8*>(pa0l + ks * 32);
        bf16x8 a1h = *reinterpret_cast<const bf16x8*>(pa1h + ks * 32);
        bf16x8 a1l = *reinterpret_cast<const bf16x8*>(pa1l + ks * 32);
#pragma unroll
        for (int nf = 0; nf < 8; ++nf) {
            size_t widx = (((size_t)ks * 16 + nf0 + nf) * 64 + lane) * 8;
            bf16x8 bh = *reinterpret_cast<const bf16x8*>(Whi + widx);
            bf16x8 bl = *reinterpret_cast<const bf16x8*>(Wlo + widx);
            acc[0][nf] = __builtin_amdgcn_mfma_f32_16x16x32_bf16(a0h, bh, acc[0][nf], 0, 0, 0);
            acc[0][nf] = __builtin_amdgcn_mfma_f32_16x16x32_bf16(a0h, bl, acc[0][nf], 0, 0, 0);
            acc[0][nf] = __builtin_amdgcn_mfma_f32_16x16x32_bf16(a0l, bh, acc[0][nf], 0, 0, 0);
            acc[1][nf] = __builtin_amdgcn_mfma_f32_16x16x32_bf16(a1h, bh, acc[1][nf], 0, 0, 0);
            acc[1][nf] = __builtin_amdgcn_mfma_f32_16x16x32_bf16(a1h, bl, acc[1][nf], 0, 0, 0);
            acc[1][nf] = __builtin_amdgcn_mfma_f32_16x16x32_bf16(a1l, bh, acc[1][nf], 0, 0, 0);
        }
    }

    // epilogue: D frag layout col = lane&15, row = (lane>>4)*4 + r
    const int colq = lane & 15;
    const int rowq = (lane >> 4) * 4;
#pragma unroll
    for (int m = 0; m < 2; ++m) {
#pragma unroll
        for (int nf = 0; nf < 8; ++nf) {
            int col = bn + nf * 16 + colq;
            float bia = bias[col];
#pragma unroll
            for (int r = 0; r < 4; ++r) {
                int rr = rw + m * 16 + rowq + r;
                if (rr < M) {
                    float v = acc[m][nf][r] + bia;
                    if (do_relu) v = fmaxf(v, 0.f);
                    C[(size_t)rr * 256 + col] = v;
                }
            }
        }
    }
}

// ---------------- pooling ----------------
__global__ void k_bounds(const int* __restrict__ batch, int N, int G, int* __restrict__ bstart) {
    int g = blockIdx.x * blockDim.x + threadIdx.x;
    if (g > G) return;
    int lo = 0, hi = N;
    while (lo < hi) {
        int mid = (lo + hi) >> 1;
        if (batch[mid] < g) lo = mid + 1; else hi = mid;
    }
    bstart[g] = lo;
}

#define POOL_ROWS 32
__global__ __launch_bounds__(256) void k_pool_partial(const float* __restrict__ h,
                                                      const int* __restrict__ batch, int N,
                                                      float* __restrict__ sumbuf,
                                                      int* __restrict__ maxbuf) {
    int t = threadIdx.x;
    int base = blockIdx.x * POOL_ROWS;
    int end = min(base + POOL_ROWS, N);
    float s = 0.f, m = 0.f;
    int gcur = batch[base];
    for (int i = base; i < end; ++i) {
        int g = batch[i];
        if (g != gcur) {
            atomicAdd(&sumbuf[gcur * 256 + t], s);
            atomicMax(&maxbuf[gcur * 256 + t], __float_as_int(m));
            s = 0.f; m = 0.f; gcur = g;
        }
        float v = h[(size_t)i * 256 + t];
        s += v;
        m = fmaxf(m, v);
    }
    atomicAdd(&sumbuf[gcur * 256 + t], s);
    atomicMax(&maxbuf[gcur * 256 + t], __float_as_int(m));
}

__global__ __launch_bounds__(256) void k_pool_final(const float* __restrict__ sumbuf,
                                                    const int* __restrict__ maxbuf,
                                                    const int* __restrict__ bstart,
                                                    float* __restrict__ gfeat) {
    int g = blockIdx.x;
    int t = threadIdx.x;
    int cnt = bstart[g + 1] - bstart[g];
    float mean = sumbuf[g * 256 + t] / fmaxf((float)cnt, 1.0f);
    float mx = __int_as_float(maxbuf[g * 256 + t]);
    if (cnt == 0) { mean = 0.f; mx = 0.f; }
    gfeat[g * 512 + t] = mean;
    gfeat[g * 512 + 256 + t] = mx;
}

// ---------------- MLP ----------------
__global__ void k_mlp(const float* __restrict__ in, const float* __restrict__ W,
                      const float* __restrict__ b, float* __restrict__ out, int Kdim, int Ndim,
                      int do_relu) {
    extern __shared__ float row[];
    int g = blockIdx.x, t = threadIdx.x;
    for (int k = t; k < Kdim; k += blockDim.x) row[k] = in[(size_t)g * Kdim + k];
    __syncthreads();
    if (t < Ndim) {
        float acc = b[t];
        for (int k = 0; k < Kdim; ++k) acc += row[k] * W[(size_t)k * Ndim + t];
        if (do_relu) acc = fmaxf(acc, 0.f);
        out[(size_t)g * Ndim + t] = acc;
    }
}

extern "C" void kernel_launch(void* const* d_in, const int* in_sizes, int n_in, void* d_out,
                              int out_size, void* d_ws, size_t ws_size, hipStream_t stream) {
    const float* x = (const float*)d_in[0];
    const int* eidx = (const int*)d_in[1];
    const int* batch = (const int*)d_in[2];
    const float* W1 = (const float*)d_in[3];
    const float* b1 = (const float*)d_in[4];
    const float* W2 = (const float*)d_in[5];
    const float* b2 = (const float*)d_in[6];
    const float* W3 = (const float*)d_in[7];
    const float* b3 = (const float*)d_in[8];
    const float* Wc1 = (const float*)d_in[9];
    const float* bc1 = (const float*)d_in[10];
    const float* Wc2 = (const float*)d_in[11];
    const float* bc2 = (const float*)d_in[12];
    const float* Wc3 = (const float*)d_in[13];
    const float* bc3 = (const float*)d_in[14];
    float* out = (float*)d_out;

    const int N = in_sizes[2];
    const int E = in_sizes[1] / 2;
    const int G = out_size / 5;
    const int* src = eidx;
    const int* dst = eidx + E;

    char* p = (char*)d_ws;
    auto alloc = [&](size_t bytes) {
        void* r = (void*)p;
        p += (bytes + 255) & ~(size_t)255;
        return r;
    };
    float* dis = (float*)alloc((size_t)N * 4);
    int* degc = (int*)alloc((size_t)N * 4);
    int* row_ptr = (int*)alloc((size_t)(N + 1) * 4);
    int* fill = (int*)alloc((size_t)N * 4);
    const int nch = CDIV(N, 1024);
    int* csum = (int*)alloc((size_t)nch * 4);
    int* coff = (int*)alloc((size_t)nch * 4);
    int* bstart = (int*)alloc((size_t)(G + 1) * 4);
    int* esrc = (int*)alloc((size_t)E * 4);
    float* ecoef = (float*)alloc((size_t)E * 4);
    float* sumbuf = (float*)alloc((size_t)G * 256 * 4);
    int* maxbuf = (int*)alloc((size_t)G * 256 * 4);
    float* gfeat = (float*)alloc((size_t)G * 512 * 4);
    float* g1 = (float*)alloc((size_t)G * 512 * 4);
    float* g2 = (float*)alloc((size_t)G * 256 * 4);
    // bf16 split buffers
    ushort* Ahi = (ushort*)alloc((size_t)N * 256 * 2);
    ushort* Alo = (ushort*)alloc((size_t)N * 256 * 2);
    ushort* W1hi = (ushort*)alloc((size_t)128 * 256 * 2);
    ushort* W1lo = (ushort*)alloc((size_t)128 * 256 * 2);
    ushort* W2hi = (ushort*)alloc((size_t)256 * 256 * 2);
    ushort* W2lo = (ushort*)alloc((size_t)256 * 256 * 2);
    ushort* W3hi = (ushort*)alloc((size_t)256 * 256 * 2);
    ushort* W3lo = (ushort*)alloc((size_t)256 * 256 * 2);
    float* buf0 = (float*)alloc((size_t)N * 256 * 4);
    (void)ws_size;

    hipMemsetAsync(degc, 0, (size_t)N * 4, stream);
    hipMemsetAsync(fill, 0, (size_t)N * 4, stream);
    hipMemsetAsync(sumbuf, 0, (size_t)G * 256 * 4, stream);
    hipMemsetAsync(maxbuf, 0, (size_t)G * 256 * 4, stream);

    // weight split+swizzle (independent of graph pipeline)
    k_wsplit<<<CDIV(128 * 256, 256), 256, 0, stream>>>(W1, 128, W1hi, W1lo);
    k_wsplit<<<CDIV(256 * 256, 256), 256, 0, stream>>>(W2, 256, W2hi, W2lo);
    k_wsplit<<<CDIV(256 * 256, 256), 256, 0, stream>>>(W3, 256, W3hi, W3lo);

    k_deg<<<CDIV(E, 256), 256, 0, stream>>>(dst, E, degc);
    k_dis<<<CDIV(N, 256), 256, 0, stream>>>(degc, N, dis);
    k_scan_partial<<<nch, 256, 0, stream>>>(degc, N, csum);
    k_scan_chunks<<<1, 64, 0, stream>>>(csum, nch, coff, row_ptr, N, E);
    k_scan_final<<<nch, 256, 0, stream>>>(degc, N, coff, row_ptr);
    k_fill<<<CDIV(E, 256), 256, 0, stream>>>(src, dst, E, row_ptr, fill, dis, esrc, ecoef);

    dim3 ggrid(CDIV(N, 128), 2);

    // layer 1: aggregate x (128 cols) -> hi/lo, GEMM K=128
    k_agg<128><<<CDIV(N * 64, 256), 256, 0, stream>>>(x, dis, row_ptr, esrc, ecoef, N, Ahi, Alo);
    k_gemm_bf16<128><<<ggrid, 256, 0, stream>>>(Ahi, Alo, W1hi, W1lo, b1, N, buf0, 1);
    // layer 2
    k_agg<256><<<CDIV(N * 64, 256), 256, 0, stream>>>(buf0, dis, row_ptr, esrc, ecoef, N, Ahi, Alo);
    k_gemm_bf16<256><<<ggrid, 256, 0, stream>>>(Ahi, Alo, W2hi, W2lo, b2, N, buf0, 1);
    // layer 3
    k_agg<256><<<CDIV(N * 64, 256), 256, 0, stream>>>(buf0, dis, row_ptr, esrc, ecoef, N, Ahi, Alo);
    k_gemm_bf16<256><<<ggrid, 256, 0, stream>>>(Ahi, Alo, W3hi, W3lo, b3, N, buf0, 1);

    // pooling
    k_bounds<<<1, 128, 0, stream>>>(batch, N, G, bstart);
    k_pool_partial<<<CDIV(N, POOL_ROWS), 256, 0, stream>>>(buf0, batch, N, sumbuf, maxbuf);
    k_pool_final<<<G, 256, 0, stream>>>(sumbuf, maxbuf, bstart, gfeat);

    // MLP head
    k_mlp<<<G, 512, 512 * 4, stream>>>(gfeat, Wc1, bc1, g1, 512, 512, 1);
    k_mlp<<<G, 256, 512 * 4, stream>>>(g1, Wc2, bc2, g2, 512, 256, 1);
    k_mlp<<<G, 64, 256 * 4, stream>>>(g2, Wc3, bc3, out, 256, 5, 0);
}

// Round 4
// 668.726 us; speedup vs baseline: 1.4610x; 1.0003x over previous
//
#include <hip/hip_runtime.h>
#include <cstdint>

#define CDIV(a, b) (((a) + (b) - 1) / (b))

typedef short bf16x8 __attribute__((ext_vector_type(8)));
typedef float f32x4 __attribute__((ext_vector_type(4)));

__device__ inline ushort f2bf_rn(float f) {
    uint32_t u = __float_as_uint(f);
    uint32_t rounding = 0x7FFF + ((u >> 16) & 1);
    return (ushort)((u + rounding) >> 16);
}
__device__ inline float bf2f(ushort h) { return __uint_as_float((uint32_t)h << 16); }

// ---------------- init: zero degc + sumbuf + maxbuf ----------------
__global__ void k_init(int* __restrict__ degc, int N, float* __restrict__ sumbuf,
                       int* __restrict__ maxbuf, int PB) {
    int i = blockIdx.x * blockDim.x + threadIdx.x;
    if (i < N) degc[i] = 0;
    if (i < PB) { sumbuf[i] = 0.f; maxbuf[i] = 0; }
}

// ---------------- degree / dis ----------------
__global__ void k_deg(const int* __restrict__ dst, int E, int* __restrict__ degc) {
    int e = blockIdx.x * blockDim.x + threadIdx.x;
    if (e < E) atomicAdd(&degc[dst[e]], 1);
}

__global__ void k_dis(const int* __restrict__ degc, int N, float* __restrict__ dis) {
    int i = blockIdx.x * blockDim.x + threadIdx.x;
    if (i < N) dis[i] = rsqrtf((float)degc[i] + 1.0f);
}

// ---------------- exclusive scan over degc -> row_ptr ----------------
__global__ void k_scan_partial(const int* __restrict__ degc, int N, int* __restrict__ csum) {
    __shared__ int sm[256];
    int t = threadIdx.x;
    int idx = blockIdx.x * 1024 + t * 4;
    int s = 0;
#pragma unroll
    for (int j = 0; j < 4; ++j)
        if (idx + j < N) s += degc[idx + j];
    sm[t] = s;
    __syncthreads();
    for (int off = 128; off > 0; off >>= 1) {
        if (t < off) sm[t] += sm[t + off];
        __syncthreads();
    }
    if (t == 0) csum[blockIdx.x] = sm[0];
}

__global__ void k_scan_chunks(const int* __restrict__ csum, int nch, int* __restrict__ coff,
                              int* __restrict__ row_ptr, int N, int E) {
    if (threadIdx.x == 0 && blockIdx.x == 0) {
        int run = 0;
        for (int i = 0; i < nch; ++i) { coff[i] = run; run += csum[i]; }
        row_ptr[N] = E;
    }
}

__global__ void k_scan_final(const int* __restrict__ degc, int N, const int* __restrict__ coff,
                             int* __restrict__ row_ptr, int* __restrict__ fill) {
    __shared__ int sm[256];
    int t = threadIdx.x;
    int idx = blockIdx.x * 1024 + t * 4;
    int v[4];
    int s = 0;
#pragma unroll
    for (int j = 0; j < 4; ++j) {
        v[j] = (idx + j < N) ? degc[idx + j] : 0;
        s += v[j];
    }
    sm[t] = s;
    __syncthreads();
    for (int off = 1; off < 256; off <<= 1) {
        int x = (t >= off) ? sm[t - off] : 0;
        __syncthreads();
        sm[t] += x;
        __syncthreads();
    }
    int excl = sm[t] - s + coff[blockIdx.x];
#pragma unroll
    for (int j = 0; j < 4; ++j) {
        if (idx + j < N) { row_ptr[idx + j] = excl; fill[idx + j] = 0; excl += v[j]; }
    }
}

// ---------------- CSR fill ----------------
__global__ void k_fill(const int* __restrict__ src, const int* __restrict__ dst, int E,
                       const int* __restrict__ row_ptr, int* __restrict__ fill,
                       const float* __restrict__ dis, int* __restrict__ esrc,
                       float* __restrict__ ecoef) {
    int e = blockIdx.x * blockDim.x + threadIdx.x;
    if (e >= E) return;
    int d = dst[e], s = src[e];
    int pos = row_ptr[d] + atomicAdd(&fill[d], 1);
    esrc[pos] = s;
    ecoef[pos] = dis[s] * dis[d];
}

// ---------------- aggregation (f32 gather, bf16 hi/lo split output) ----------------
template <int C>
__global__ __launch_bounds__(256) void k_agg(const float* __restrict__ x,
                                             const float* __restrict__ dis,
                                             const int* __restrict__ row_ptr,
                                             const int* __restrict__ esrc,
                                             const float* __restrict__ ecoef, int N,
                                             ushort* __restrict__ ohi,
                                             ushort* __restrict__ olo) {
    constexpr int V = C / 64;
    int wave = (blockIdx.x * blockDim.x + threadIdx.x) >> 6;
    int lane = threadIdx.x & 63;
    if (wave >= N) return;
    const int i = wave;
    float di = dis[i];
    float dd = di * di;
    float acc[V];
    {
        const float* xr = x + (size_t)i * C + lane * V;
        if constexpr (V == 4) {
            float4 v = *reinterpret_cast<const float4*>(xr);
            acc[0] = dd * v.x; acc[1] = dd * v.y; acc[2] = dd * v.z; acc[3] = dd * v.w;
        } else {
            float2 v = *reinterpret_cast<const float2*>(xr);
            acc[0] = dd * v.x; acc[1] = dd * v.y;
        }
    }
    int p0 = row_ptr[i], p1 = row_ptr[i + 1];
    int p = p0;
    if constexpr (V == 4) {
        for (; p + 4 <= p1; p += 4) {
            int s0 = esrc[p], s1 = esrc[p + 1], s2 = esrc[p + 2], s3 = esrc[p + 3];
            float c0 = ecoef[p], c1 = ecoef[p + 1], c2 = ecoef[p + 2], c3 = ecoef[p + 3];
            float4 v0 = *reinterpret_cast<const float4*>(x + (size_t)s0 * C + lane * V);
            float4 v1 = *reinterpret_cast<const float4*>(x + (size_t)s1 * C + lane * V);
            float4 v2 = *reinterpret_cast<const float4*>(x + (size_t)s2 * C + lane * V);
            float4 v3 = *reinterpret_cast<const float4*>(x + (size_t)s3 * C + lane * V);
            acc[0] += c0 * v0.x; acc[1] += c0 * v0.y; acc[2] += c0 * v0.z; acc[3] += c0 * v0.w;
            acc[0] += c1 * v1.x; acc[1] += c1 * v1.y; acc[2] += c1 * v1.z; acc[3] += c1 * v1.w;
            acc[0] += c2 * v2.x; acc[1] += c2 * v2.y; acc[2] += c2 * v2.z; acc[3] += c2 * v2.w;
            acc[0] += c3 * v3.x; acc[1] += c3 * v3.y; acc[2] += c3 * v3.z; acc[3] += c3 * v3.w;
        }
        for (; p < p1; ++p) {
            int s = esrc[p];
            float c = ecoef[p];
            float4 v = *reinterpret_cast<const float4*>(x + (size_t)s * C + lane * V);
            acc[0] += c * v.x; acc[1] += c * v.y; acc[2] += c * v.z; acc[3] += c * v.w;
        }
    } else {
        for (; p + 4 <= p1; p += 4) {
            int s0 = esrc[p], s1 = esrc[p + 1], s2 = esrc[p + 2], s3 = esrc[p + 3];
            float c0 = ecoef[p], c1 = ecoef[p + 1], c2 = ecoef[p + 2], c3 = ecoef[p + 3];
            float2 v0 = *reinterpret_cast<const float2*>(x + (size_t)s0 * C + lane * V);
            float2 v1 = *reinterpret_cast<const float2*>(x + (size_t)s1 * C + lane * V);
            float2 v2 = *reinterpret_cast<const float2*>(x + (size_t)s2 * C + lane * V);
            float2 v3 = *reinterpret_cast<const float2*>(x + (size_t)s3 * C + lane * V);
            acc[0] += c0 * v0.x; acc[1] += c0 * v0.y;
            acc[0] += c1 * v1.x; acc[1] += c1 * v1.y;
            acc[0] += c2 * v2.x; acc[1] += c2 * v2.y;
            acc[0] += c3 * v3.x; acc[1] += c3 * v3.y;
        }
        for (; p < p1; ++p) {
            int s = esrc[p];
            float c = ecoef[p];
            float2 v = *reinterpret_cast<const float2*>(x + (size_t)s * C + lane * V);
            acc[0] += c * v.x; acc[1] += c * v.y;
        }
    }
    ushort hi[V], lo[V];
#pragma unroll
    for (int j = 0; j < V; ++j) {
        hi[j] = f2bf_rn(acc[j]);
        lo[j] = f2bf_rn(acc[j] - bf2f(hi[j]));
    }
    size_t ob = (size_t)i * C + lane * V;
    if constexpr (V == 4) {
        *reinterpret_cast<ushort4*>(ohi + ob) = make_ushort4(hi[0], hi[1], hi[2], hi[3]);
        *reinterpret_cast<ushort4*>(olo + ob) = make_ushort4(lo[0], lo[1], lo[2], lo[3]);
    } else {
        *reinterpret_cast<ushort2*>(ohi + ob) = make_ushort2(hi[0], hi[1]);
        *reinterpret_cast<ushort2*>(olo + ob) = make_ushort2(lo[0], lo[1]);
    }
}

// ---------------- W split + fragment swizzle ----------------
__global__ void k_wsplit(const float* __restrict__ W, int K, ushort* __restrict__ Whi,
                         ushort* __restrict__ Wlo) {
    int idx = blockIdx.x * 256 + threadIdx.x;
    if (idx >= K * 256) return;
    int k = idx >> 8, n = idx & 255;
    float v = W[idx];
    ushort hi = f2bf_rn(v);
    ushort lo = f2bf_rn(v - bf2f(hi));
    int ks = k >> 5, r = k & 31;
    int lane = (r >> 3) * 16 + (n & 15);
    int j = r & 7;
    size_t d = (((size_t)ks * 16 + (n >> 4)) * 64 + lane) * 8 + j;
    Whi[d] = hi;
    Wlo[d] = lo;
}

// ---------------- split-bf16 MFMA GEMM, optional fused pooling epilogue ----------------
// POOL=false: C[M,256] = relu(A@W + bias) written to C.
// POOL=true : per-graph column sum & max of relu(A@W+bias) accumulated into
//             sumbuf/maxbuf via atomics (values >=0 so int atomicMax == float max,
//             and init 0 is the identity). No C write.
template <int K, bool POOL>
__global__ __launch_bounds__(256) void k_gemm_bf16(const ushort* __restrict__ Ahi,
                                                   const ushort* __restrict__ Alo,
                                                   const ushort* __restrict__ Whi,
                                                   const ushort* __restrict__ Wlo,
                                                   const float* __restrict__ bias, int M,
                                                   float* __restrict__ C, int do_relu,
                                                   const int* __restrict__ batch,
                                                   float* __restrict__ sumbuf,
                                                   int* __restrict__ maxbuf) {
    const int t = threadIdx.x;
    const int w = t >> 6, lane = t & 63;
    const int bm = blockIdx.x * 128;
    const int bn = blockIdx.y * 128;
    const int rw = bm + w * 32;

    f32x4 acc[2][8] = {};

    int row0 = min(rw + (lane & 15), M - 1);
    int row1 = min(rw + 16 + (lane & 15), M - 1);
    const int kbase = (lane >> 4) * 8;
    const ushort* pa0h = Ahi + (size_t)row0 * K + kbase;
    const ushort* pa0l = Alo + (size_t)row0 * K + kbase;
    const ushort* pa1h = Ahi + (size_t)row1 * K + kbase;
    const ushort* pa1l = Alo + (size_t)row1 * K + kbase;
    const int nf0 = bn >> 4;

    for (int ks = 0; ks < K / 32; ++ks) {
        bf16x8 a0h = *reinterpret_cast<const bf16x8*>(pa0h + ks * 32);
        bf16x8 a0l = *reinterpret_cast<const bf16x8*>(pa0l + ks * 32);
        bf16x8 a1h = *reinterpret_cast<const bf16x8*>(pa1h + ks * 32);
        bf16x8 a1l = *reinterpret_cast<const bf16x8*>(pa1l + ks * 32);
#pragma unroll
        for (int nf = 0; nf < 8; ++nf) {
            size_t widx = (((size_t)ks * 16 + nf0 + nf) * 64 + lane) * 8;
            bf16x8 bh = *reinterpret_cast<const bf16x8*>(Whi + widx);
            bf16x8 bl = *reinterpret_cast<const bf16x8*>(Wlo + widx);
            acc[0][nf] = __builtin_amdgcn_mfma_f32_16x16x32_bf16(a0h, bh, acc[0][nf], 0, 0, 0);
            acc[0][nf] = __builtin_amdgcn_mfma_f32_16x16x32_bf16(a0h, bl, acc[0][nf], 0, 0, 0);
            acc[0][nf] = __builtin_amdgcn_mfma_f32_16x16x32_bf16(a0l, bh, acc[0][nf], 0, 0, 0);
            acc[1][nf] = __builtin_amdgcn_mfma_f32_16x16x32_bf16(a1h, bh, acc[1][nf], 0, 0, 0);
            acc[1][nf] = __builtin_amdgcn_mfma_f32_16x16x32_bf16(a1h, bl, acc[1][nf], 0, 0, 0);
            acc[1][nf] = __builtin_amdgcn_mfma_f32_16x16x32_bf16(a1l, bh, acc[1][nf], 0, 0, 0);
        }
    }

    const int colq = lane & 15;
    const int rowq = (lane >> 4) * 4;

    if constexpr (!POOL) {
#pragma unroll
        for (int m = 0; m < 2; ++m) {
#pragma unroll
            for (int nf = 0; nf < 8; ++nf) {
                int col = bn + nf * 16 + colq;
                float bia = bias[col];
#pragma unroll
                for (int r = 0; r < 4; ++r) {
                    int rr = rw + m * 16 + rowq + r;
                    if (rr < M) {
                        float v = acc[m][nf][r] + bia;
                        if (do_relu) v = fmaxf(v, 0.f);
                        C[(size_t)rr * 256 + col] = v;
                    }
                }
            }
        }
    } else {
        // graph ids covering this thread's 8 rows (two runs of 4, consecutive)
        int r0 = min(rw + rowq, M - 1);
        int r7 = min(rw + 16 + rowq + 3, M - 1);
        int g0 = batch[r0];
        int g7 = batch[r7];
        int gfirst = __shfl(g0, 0);  // == batch[min(rw, M-1)]
        bool uni = __all(g0 == gfirst && g7 == gfirst);
        if (uni) {
#pragma unroll
            for (int nf = 0; nf < 8; ++nf) {
                int col = bn + nf * 16 + colq;
                float bia = bias[col];
                float s = 0.f, mx = 0.f;
#pragma unroll
                for (int m = 0; m < 2; ++m) {
#pragma unroll
                    for (int r = 0; r < 4; ++r) {
                        int rr = rw + m * 16 + rowq + r;
                        float v = fmaxf(acc[m][nf][r] + bia, 0.f);
                        if (rr < M) { s += v; mx = fmaxf(mx, v); }
                    }
                }
                // reduce across the 4 row-groups (lane bits 4,5)
                s += __shfl_xor(s, 16);
                mx = fmaxf(mx, __shfl_xor(mx, 16));
                s += __shfl_xor(s, 32);
                mx = fmaxf(mx, __shfl_xor(mx, 32));
                if ((lane >> 4) == 0) {
                    atomicAdd(&sumbuf[gfirst * 256 + col], s);
                    atomicMax(&maxbuf[gfirst * 256 + col], __float_as_int(mx));
                }
            }
        } else {
            // rare: wave tile crosses a graph boundary — per-row atomics
#pragma unroll
            for (int nf = 0; nf < 8; ++nf) {
                int col = bn + nf * 16 + colq;
                float bia = bias[col];
#pragma unroll
                for (int m = 0; m < 2; ++m) {
#pragma unroll
                    for (int r = 0; r < 4; ++r) {
                        int rr = rw + m * 16 + rowq + r;
                        if (rr < M) {
                            float v = fmaxf(acc[m][nf][r] + bia, 0.f);
                            int g = batch[rr];
                            atomicAdd(&sumbuf[g * 256 + col], v);
                            atomicMax(&maxbuf[g * 256 + col], __float_as_int(v));
                        }
                    }
                }
            }
        }
    }
}

// ---------------- pool finalize (binary-search bounds inline) ----------------
__global__ __launch_bounds__(256) void k_pool_final(const float* __restrict__ sumbuf,
                                                    const int* __restrict__ maxbuf,
                                                    const int* __restrict__ batch, int N,
                                                    float* __restrict__ gfeat) {
    int g = blockIdx.x;
    int t = threadIdx.x;
    int lo = 0, hi = N;
    while (lo < hi) { int mid = (lo + hi) >> 1; if (batch[mid] < g) lo = mid + 1; else hi = mid; }
    int s = lo;
    lo = 0; hi = N;
    while (lo < hi) { int mid = (lo + hi) >> 1; if (batch[mid] < g + 1) lo = mid + 1; else hi = mid; }
    int cnt = lo - s;
    float mean = sumbuf[g * 256 + t] / fmaxf((float)cnt, 1.0f);
    float mx = __int_as_float(maxbuf[g * 256 + t]);
    if (cnt == 0) { mean = 0.f; mx = 0.f; }
    gfeat[g * 512 + t] = mean;
    gfeat[g * 512 + 256 + t] = mx;
}

// ---------------- MLP ----------------
__global__ void k_mlp(const float* __restrict__ in, const float* __restrict__ W,
                      const float* __restrict__ b, float* __restrict__ out, int Kdim, int Ndim,
                      int do_relu) {
    extern __shared__ float row[];
    int g = blockIdx.x, t = threadIdx.x;
    for (int k = t; k < Kdim; k += blockDim.x) row[k] = in[(size_t)g * Kdim + k];
    __syncthreads();
    if (t < Ndim) {
        float acc = b[t];
        for (int k = 0; k < Kdim; ++k) acc += row[k] * W[(size_t)k * Ndim + t];
        if (do_relu) acc = fmaxf(acc, 0.f);
        out[(size_t)g * Ndim + t] = acc;
    }
}

extern "C" void kernel_launch(void* const* d_in, const int* in_sizes, int n_in, void* d_out,
                              int out_size, void* d_ws, size_t ws_size, hipStream_t stream) {
    const float* x = (const float*)d_in[0];
    const int* eidx = (const int*)d_in[1];
    const int* batch = (const int*)d_in[2];
    const float* W1 = (const float*)d_in[3];
    const float* b1 = (const float*)d_in[4];
    const float* W2 = (const float*)d_in[5];
    const float* b2 = (const float*)d_in[6];
    const float* W3 = (const float*)d_in[7];
    const float* b3 = (const float*)d_in[8];
    const float* Wc1 = (const float*)d_in[9];
    const float* bc1 = (const float*)d_in[10];
    const float* Wc2 = (const float*)d_in[11];
    const float* bc2 = (const float*)d_in[12];
    const float* Wc3 = (const float*)d_in[13];
    const float* bc3 = (const float*)d_in[14];
    float* out = (float*)d_out;

    const int N = in_sizes[2];
    const int E = in_sizes[1] / 2;
    const int G = out_size / 5;
    const int* src = eidx;
    const int* dst = eidx + E;

    char* p = (char*)d_ws;
    auto alloc = [&](size_t bytes) {
        void* r = (void*)p;
        p += (bytes + 255) & ~(size_t)255;
        return r;
    };
    float* dis = (float*)alloc((size_t)N * 4);
    int* degc = (int*)alloc((size_t)N * 4);
    int* row_ptr = (int*)alloc((size_t)(N + 1) * 4);
    int* fill = (int*)alloc((size_t)N * 4);
    const int nch = CDIV(N, 1024);
    int* csum = (int*)alloc((size_t)nch * 4);
    int* coff = (int*)alloc((size_t)nch * 4);
    int* esrc = (int*)alloc((size_t)E * 4);
    float* ecoef = (float*)alloc((size_t)E * 4);
    float* sumbuf = (float*)alloc((size_t)G * 256 * 4);
    int* maxbuf = (int*)alloc((size_t)G * 256 * 4);
    float* gfeat = (float*)alloc((size_t)G * 512 * 4);
    float* g1 = (float*)alloc((size_t)G * 512 * 4);
    float* g2 = (float*)alloc((size_t)G * 256 * 4);
    ushort* Ahi = (ushort*)alloc((size_t)N * 256 * 2);
    ushort* Alo = (ushort*)alloc((size_t)N * 256 * 2);
    ushort* W1hi = (ushort*)alloc((size_t)128 * 256 * 2);
    ushort* W1lo = (ushort*)alloc((size_t)128 * 256 * 2);
    ushort* W2hi = (ushort*)alloc((size_t)256 * 256 * 2);
    ushort* W2lo = (ushort*)alloc((size_t)256 * 256 * 2);
    ushort* W3hi = (ushort*)alloc((size_t)256 * 256 * 2);
    ushort* W3lo = (ushort*)alloc((size_t)256 * 256 * 2);
    float* buf0 = (float*)alloc((size_t)N * 256 * 4);
    (void)ws_size;

    k_init<<<CDIV(N, 256), 256, 0, stream>>>(degc, N, sumbuf, maxbuf, G * 256);

    // weight split+swizzle (independent of graph pipeline)
    k_wsplit<<<CDIV(128 * 256, 256), 256, 0, stream>>>(W1, 128, W1hi, W1lo);
    k_wsplit<<<CDIV(256 * 256, 256), 256, 0, stream>>>(W2, 256, W2hi, W2lo);
    k_wsplit<<<CDIV(256 * 256, 256), 256, 0, stream>>>(W3, 256, W3hi, W3lo);

    k_deg<<<CDIV(E, 256), 256, 0, stream>>>(dst, E, degc);
    k_dis<<<CDIV(N, 256), 256, 0, stream>>>(degc, N, dis);
    k_scan_partial<<<nch, 256, 0, stream>>>(degc, N, csum);
    k_scan_chunks<<<1, 64, 0, stream>>>(csum, nch, coff, row_ptr, N, E);
    k_scan_final<<<nch, 256, 0, stream>>>(degc, N, coff, row_ptr, fill);
    k_fill<<<CDIV(E, 256), 256, 0, stream>>>(src, dst, E, row_ptr, fill, dis, esrc, ecoef);

    dim3 ggrid(CDIV(N, 128), 2);

    // layer 1
    k_agg<128><<<CDIV(N * 64, 256), 256, 0, stream>>>(x, dis, row_ptr, esrc, ecoef, N, Ahi, Alo);
    k_gemm_bf16<128, false><<<ggrid, 256, 0, stream>>>(Ahi, Alo, W1hi, W1lo, b1, N, buf0, 1,
                                                       batch, sumbuf, maxbuf);
    // layer 2
    k_agg<256><<<CDIV(N * 64, 256), 256, 0, stream>>>(buf0, dis, row_ptr, esrc, ecoef, N, Ahi, Alo);
    k_gemm_bf16<256, false><<<ggrid, 256, 0, stream>>>(Ahi, Alo, W2hi, W2lo, b2, N, buf0, 1,
                                                       batch, sumbuf, maxbuf);
    // layer 3: GEMM with fused pooling (no buf0 write)
    k_agg<256><<<CDIV(N * 64, 256), 256, 0, stream>>>(buf0, dis, row_ptr, esrc, ecoef, N, Ahi, Alo);
    k_gemm_bf16<256, true><<<ggrid, 256, 0, stream>>>(Ahi, Alo, W3hi, W3lo, b3, N, buf0, 1,
                                                      batch, sumbuf, maxbuf);

    k_pool_final<<<G, 256, 0, stream>>>(sumbuf, maxbuf, batch, N, gfeat);

    // MLP head
    k_mlp<<<G, 512, 512 * 4, stream>>>(gfeat, Wc1, bc1, g1, 512, 512, 1);
    k_mlp<<<G, 256, 512 * 4, stream>>>(g1, Wc2, bc2, g2, 512, 256, 1);
    k_mlp<<<G, 64, 256 * 4, stream>>>(g2, Wc3, bc3, out, 256, 5, 0);
}

// Round 5
// 651.065 us; speedup vs baseline: 1.5006x; 1.0271x over previous
//
#include <hip/hip_runtime.h>
#include <cstdint>

#define CDIV(a, b) (((a) + (b) - 1) / (b))

typedef short bf16x8 __attribute__((ext_vector_type(8)));
typedef float f32x4 __attribute__((ext_vector_type(4)));

__device__ inline ushort f2bf_rn(float f) {
    uint32_t u = __float_as_uint(f);
    uint32_t rounding = 0x7FFF + ((u >> 16) & 1);
    return (ushort)((u + rounding) >> 16);
}
__device__ inline float bf2f(ushort h) { return __uint_as_float((uint32_t)h << 16); }

// ---------------- init: zero degc + sumbuf + maxbuf ----------------
__global__ void k_init(int* __restrict__ degc, int N, float* __restrict__ sumbuf,
                       int* __restrict__ maxbuf, int PB) {
    int i = blockIdx.x * blockDim.x + threadIdx.x;
    if (i < N) degc[i] = 0;
    if (i < PB) { sumbuf[i] = 0.f; maxbuf[i] = 0; }
}

// ---------------- degree ----------------
__global__ void k_deg(const int* __restrict__ dst, int E, int* __restrict__ degc) {
    int e = blockIdx.x * blockDim.x + threadIdx.x;
    if (e < E) atomicAdd(&degc[dst[e]], 1);
}

// ---------------- exclusive scan over degc -> row_ptr (+dis, +fill=0) ----------------
__global__ void k_scan_partial(const int* __restrict__ degc, int N, int* __restrict__ csum) {
    __shared__ int sm[256];
    int t = threadIdx.x;
    int idx = blockIdx.x * 1024 + t * 4;
    int s = 0;
#pragma unroll
    for (int j = 0; j < 4; ++j)
        if (idx + j < N) s += degc[idx + j];
    sm[t] = s;
    __syncthreads();
    for (int off = 128; off > 0; off >>= 1) {
        if (t < off) sm[t] += sm[t + off];
        __syncthreads();
    }
    if (t == 0) csum[blockIdx.x] = sm[0];
}

__global__ void k_scan_chunks(const int* __restrict__ csum, int nch, int* __restrict__ coff,
                              int* __restrict__ row_ptr, int N, int E) {
    if (threadIdx.x == 0 && blockIdx.x == 0) {
        int run = 0;
        for (int i = 0; i < nch; ++i) { coff[i] = run; run += csum[i]; }
        row_ptr[N] = E;
    }
}

__global__ void k_scan_final(const int* __restrict__ degc, int N, const int* __restrict__ coff,
                             int* __restrict__ row_ptr, int* __restrict__ fill,
                             float* __restrict__ dis) {
    __shared__ int sm[256];
    int t = threadIdx.x;
    int idx = blockIdx.x * 1024 + t * 4;
    int v[4];
    int s = 0;
#pragma unroll
    for (int j = 0; j < 4; ++j) {
        v[j] = (idx + j < N) ? degc[idx + j] : 0;
        s += v[j];
    }
    sm[t] = s;
    __syncthreads();
    for (int off = 1; off < 256; off <<= 1) {
        int x = (t >= off) ? sm[t - off] : 0;
        __syncthreads();
        sm[t] += x;
        __syncthreads();
    }
    int excl = sm[t] - s + coff[blockIdx.x];
#pragma unroll
    for (int j = 0; j < 4; ++j) {
        if (idx + j < N) {
            row_ptr[idx + j] = excl;
            fill[idx + j] = 0;
            dis[idx + j] = rsqrtf((float)v[j] + 1.0f);
            excl += v[j];
        }
    }
}

// ---------------- CSR fill ----------------
__global__ void k_fill(const int* __restrict__ src, const int* __restrict__ dst, int E,
                       const int* __restrict__ row_ptr, int* __restrict__ fill,
                       const float* __restrict__ dis, int* __restrict__ esrc,
                       float* __restrict__ ecoef) {
    int e = blockIdx.x * blockDim.x + threadIdx.x;
    if (e >= E) return;
    int d = dst[e], s = src[e];
    int pos = row_ptr[d] + atomicAdd(&fill[d], 1);
    esrc[pos] = s;
    ecoef[pos] = dis[s] * dis[d];
}

// ---------------- aggregation (f32 gather, bf16 hi/lo split output) ----------------
template <int C>
__global__ __launch_bounds__(256) void k_agg(const float* __restrict__ x,
                                             const float* __restrict__ dis,
                                             const int* __restrict__ row_ptr,
                                             const int* __restrict__ esrc,
                                             const float* __restrict__ ecoef, int N,
                                             ushort* __restrict__ ohi,
                                             ushort* __restrict__ olo) {
    constexpr int V = C / 64;
    int wave = (blockIdx.x * blockDim.x + threadIdx.x) >> 6;
    int lane = threadIdx.x & 63;
    if (wave >= N) return;
    const int i = wave;
    float di = dis[i];
    float dd = di * di;
    float acc[V];
    {
        const float* xr = x + (size_t)i * C + lane * V;
        if constexpr (V == 4) {
            float4 v = *reinterpret_cast<const float4*>(xr);
            acc[0] = dd * v.x; acc[1] = dd * v.y; acc[2] = dd * v.z; acc[3] = dd * v.w;
        } else {
            float2 v = *reinterpret_cast<const float2*>(xr);
            acc[0] = dd * v.x; acc[1] = dd * v.y;
        }
    }
    int p0 = row_ptr[i], p1 = row_ptr[i + 1];
    int p = p0;
    if constexpr (V == 4) {
        for (; p + 4 <= p1; p += 4) {
            int s0 = esrc[p], s1 = esrc[p + 1], s2 = esrc[p + 2], s3 = esrc[p + 3];
            float c0 = ecoef[p], c1 = ecoef[p + 1], c2 = ecoef[p + 2], c3 = ecoef[p + 3];
            float4 v0 = *reinterpret_cast<const float4*>(x + (size_t)s0 * C + lane * V);
            float4 v1 = *reinterpret_cast<const float4*>(x + (size_t)s1 * C + lane * V);
            float4 v2 = *reinterpret_cast<const float4*>(x + (size_t)s2 * C + lane * V);
            float4 v3 = *reinterpret_cast<const float4*>(x + (size_t)s3 * C + lane * V);
            acc[0] += c0 * v0.x; acc[1] += c0 * v0.y; acc[2] += c0 * v0.z; acc[3] += c0 * v0.w;
            acc[0] += c1 * v1.x; acc[1] += c1 * v1.y; acc[2] += c1 * v1.z; acc[3] += c1 * v1.w;
            acc[0] += c2 * v2.x; acc[1] += c2 * v2.y; acc[2] += c2 * v2.z; acc[3] += c2 * v2.w;
            acc[0] += c3 * v3.x; acc[1] += c3 * v3.y; acc[2] += c3 * v3.z; acc[3] += c3 * v3.w;
        }
        for (; p < p1; ++p) {
            int s = esrc[p];
            float c = ecoef[p];
            float4 v = *reinterpret_cast<const float4*>(x + (size_t)s * C + lane * V);
            acc[0] += c * v.x; acc[1] += c * v.y; acc[2] += c * v.z; acc[3] += c * v.w;
        }
    } else {
        for (; p + 4 <= p1; p += 4) {
            int s0 = esrc[p], s1 = esrc[p + 1], s2 = esrc[p + 2], s3 = esrc[p + 3];
            float c0 = ecoef[p], c1 = ecoef[p + 1], c2 = ecoef[p + 2], c3 = ecoef[p + 3];
            float2 v0 = *reinterpret_cast<const float2*>(x + (size_t)s0 * C + lane * V);
            float2 v1 = *reinterpret_cast<const float2*>(x + (size_t)s1 * C + lane * V);
            float2 v2 = *reinterpret_cast<const float2*>(x + (size_t)s2 * C + lane * V);
            float2 v3 = *reinterpret_cast<const float2*>(x + (size_t)s3 * C + lane * V);
            acc[0] += c0 * v0.x; acc[1] += c0 * v0.y;
            acc[0] += c1 * v1.x; acc[1] += c1 * v1.y;
            acc[0] += c2 * v2.x; acc[1] += c2 * v2.y;
            acc[0] += c3 * v3.x; acc[1] += c3 * v3.y;
        }
        for (; p < p1; ++p) {
            int s = esrc[p];
            float c = ecoef[p];
            float2 v = *reinterpret_cast<const float2*>(x + (size_t)s * C + lane * V);
            acc[0] += c * v.x; acc[1] += c * v.y;
        }
    }
    ushort hi[V], lo[V];
#pragma unroll
    for (int j = 0; j < V; ++j) {
        hi[j] = f2bf_rn(acc[j]);
        lo[j] = f2bf_rn(acc[j] - bf2f(hi[j]));
    }
    size_t ob = (size_t)i * C + lane * V;
    if constexpr (V == 4) {
        *reinterpret_cast<ushort4*>(ohi + ob) = make_ushort4(hi[0], hi[1], hi[2], hi[3]);
        *reinterpret_cast<ushort4*>(olo + ob) = make_ushort4(lo[0], lo[1], lo[2], lo[3]);
    } else {
        *reinterpret_cast<ushort2*>(ohi + ob) = make_ushort2(hi[0], hi[1]);
        *reinterpret_cast<ushort2*>(olo + ob) = make_ushort2(lo[0], lo[1]);
    }
}

// ---------------- W split + fragment swizzle ----------------
__global__ void k_wsplit(const float* __restrict__ W, int K, ushort* __restrict__ Whi,
                         ushort* __restrict__ Wlo) {
    int idx = blockIdx.x * 256 + threadIdx.x;
    if (idx >= K * 256) return;
    int k = idx >> 8, n = idx & 255;
    float v = W[idx];
    ushort hi = f2bf_rn(v);
    ushort lo = f2bf_rn(v - bf2f(hi));
    int ks = k >> 5, r = k & 31;
    int lane = (r >> 3) * 16 + (n & 15);
    int j = r & 7;
    size_t d = (((size_t)ks * 16 + (n >> 4)) * 64 + lane) * 8 + j;
    Whi[d] = hi;
    Wlo[d] = lo;
}

// ---------------- split-bf16 MFMA GEMM with LDS-staged B panel ----------------
// B panel for this block (128 cols x 32 K-rows x {hi,lo}) is staged in LDS per
// k-step, double-buffered, shared by the 4 waves (4x L2 traffic cut vs direct).
// POOL=true: fused per-graph sum/max pooling epilogue (values >=0 post-ReLU so
// int atomicMax == float max, init 0 is identity).
template <int K, bool POOL>
__global__ __launch_bounds__(256) void k_gemm_bf16(const ushort* __restrict__ Ahi,
                                                   const ushort* __restrict__ Alo,
                                                   const ushort* __restrict__ Whi,
                                                   const ushort* __restrict__ Wlo,
                                                   const float* __restrict__ bias, int M,
                                                   float* __restrict__ C, int do_relu,
                                                   const int* __restrict__ batch,
                                                   float* __restrict__ sumbuf,
                                                   int* __restrict__ maxbuf) {
    __shared__ ushort Bs[2][2][8][512];  // [buf][hi/lo][nf][lane*8] = 32 KB
    const int t = threadIdx.x;
    const int w = t >> 6, lane = t & 63;
    const int bm = blockIdx.x * 128;
    const int bn = blockIdx.y * 128;
    const int rw = bm + w * 32;

    f32x4 acc[2][8] = {};

    int row0 = min(rw + (lane & 15), M - 1);
    int row1 = min(rw + 16 + (lane & 15), M - 1);
    const int kbase = (lane >> 4) * 8;
    const ushort* pa0h = Ahi + (size_t)row0 * K + kbase;
    const ushort* pa0l = Alo + (size_t)row0 * K + kbase;
    const ushort* pa1h = Ahi + (size_t)row1 * K + kbase;
    const ushort* pa1l = Alo + (size_t)row1 * K + kbase;
    const int nf0 = bn >> 4;
    constexpr int KS = K / 32;

    auto stageB = [&](int ks, int b) {
#pragma unroll
        for (int q = 0; q < 2; ++q) {
            int nf = (w << 1) | q;
            size_t widx = (((size_t)ks * 16 + nf0 + nf) * 64 + lane) * 8;
            bf16x8 vh = *reinterpret_cast<const bf16x8*>(Whi + widx);
            bf16x8 vl = *reinterpret_cast<const bf16x8*>(Wlo + widx);
            *reinterpret_cast<bf16x8*>(&Bs[b][0][nf][lane * 8]) = vh;
            *reinterpret_cast<bf16x8*>(&Bs[b][1][nf][lane * 8]) = vl;
        }
    };

    stageB(0, 0);
    int buf = 0;
    for (int ks = 0; ks < KS; ++ks) {
        __syncthreads();
        if (ks + 1 < KS) stageB(ks + 1, buf ^ 1);
        bf16x8 a0h = *reinterpret_cast<const bf16x8*>(pa0h + ks * 32);
        bf16x8 a0l = *reinterpret_cast<const bf16x8*>(pa0l + ks * 32);
        bf16x8 a1h = *reinterpret_cast<const bf16x8*>(pa1h + ks * 32);
        bf16x8 a1l = *reinterpret_cast<const bf16x8*>(pa1l + ks * 32);
#pragma unroll
        for (int nf = 0; nf < 8; ++nf) {
            bf16x8 bh = *reinterpret_cast<const bf16x8*>(&Bs[buf][0][nf][lane * 8]);
            bf16x8 bl = *reinterpret_cast<const bf16x8*>(&Bs[buf][1][nf][lane * 8]);
            acc[0][nf] = __builtin_amdgcn_mfma_f32_16x16x32_bf16(a0h, bh, acc[0][nf], 0, 0, 0);
            acc[0][nf] = __builtin_amdgcn_mfma_f32_16x16x32_bf16(a0h, bl, acc[0][nf], 0, 0, 0);
            acc[0][nf] = __builtin_amdgcn_mfma_f32_16x16x32_bf16(a0l, bh, acc[0][nf], 0, 0, 0);
            acc[1][nf] = __builtin_amdgcn_mfma_f32_16x16x32_bf16(a1h, bh, acc[1][nf], 0, 0, 0);
            acc[1][nf] = __builtin_amdgcn_mfma_f32_16x16x32_bf16(a1h, bl, acc[1][nf], 0, 0, 0);
            acc[1][nf] = __builtin_amdgcn_mfma_f32_16x16x32_bf16(a1l, bh, acc[1][nf], 0, 0, 0);
        }
        buf ^= 1;
    }

    const int colq = lane & 15;
    const int rowq = (lane >> 4) * 4;

    if constexpr (!POOL) {
#pragma unroll
        for (int m = 0; m < 2; ++m) {
#pragma unroll
            for (int nf = 0; nf < 8; ++nf) {
                int col = bn + nf * 16 + colq;
                float bia = bias[col];
#pragma unroll
                for (int r = 0; r < 4; ++r) {
                    int rr = rw + m * 16 + rowq + r;
                    if (rr < M) {
                        float v = acc[m][nf][r] + bia;
                        if (do_relu) v = fmaxf(v, 0.f);
                        C[(size_t)rr * 256 + col] = v;
                    }
                }
            }
        }
    } else {
        int r0 = min(rw + rowq, M - 1);
        int r7 = min(rw + 16 + rowq + 3, M - 1);
        int g0 = batch[r0];
        int g7 = batch[r7];
        int gfirst = __shfl(g0, 0);
        bool uni = __all(g0 == gfirst && g7 == gfirst);
        if (uni) {
#pragma unroll
            for (int nf = 0; nf < 8; ++nf) {
                int col = bn + nf * 16 + colq;
                float bia = bias[col];
                float s = 0.f, mx = 0.f;
#pragma unroll
                for (int m = 0; m < 2; ++m) {
#pragma unroll
                    for (int r = 0; r < 4; ++r) {
                        int rr = rw + m * 16 + rowq + r;
                        float v = fmaxf(acc[m][nf][r] + bia, 0.f);
                        if (rr < M) { s += v; mx = fmaxf(mx, v); }
                    }
                }
                s += __shfl_xor(s, 16);
                mx = fmaxf(mx, __shfl_xor(mx, 16));
                s += __shfl_xor(s, 32);
                mx = fmaxf(mx, __shfl_xor(mx, 32));
                if ((lane >> 4) == 0) {
                    atomicAdd(&sumbuf[gfirst * 256 + col], s);
                    atomicMax(&maxbuf[gfirst * 256 + col], __float_as_int(mx));
                }
            }
        } else {
#pragma unroll
            for (int nf = 0; nf < 8; ++nf) {
                int col = bn + nf * 16 + colq;
                float bia = bias[col];
#pragma unroll
                for (int m = 0; m < 2; ++m) {
#pragma unroll
                    for (int r = 0; r < 4; ++r) {
                        int rr = rw + m * 16 + rowq + r;
                        if (rr < M) {
                            float v = fmaxf(acc[m][nf][r] + bia, 0.f);
                            int g = batch[rr];
                            atomicAdd(&sumbuf[g * 256 + col], v);
                            atomicMax(&maxbuf[g * 256 + col], __float_as_int(v));
                        }
                    }
                }
            }
        }
    }
}

// ---------------- pool finalize ----------------
__global__ __launch_bounds__(256) void k_pool_final(const float* __restrict__ sumbuf,
                                                    const int* __restrict__ maxbuf,
                                                    const int* __restrict__ batch, int N,
                                                    float* __restrict__ gfeat) {
    int g = blockIdx.x;
    int t = threadIdx.x;
    int lo = 0, hi = N;
    while (lo < hi) { int mid = (lo + hi) >> 1; if (batch[mid] < g) lo = mid + 1; else hi = mid; }
    int s = lo;
    lo = 0; hi = N;
    while (lo < hi) { int mid = (lo + hi) >> 1; if (batch[mid] < g + 1) lo = mid + 1; else hi = mid; }
    int cnt = lo - s;
    float mean = sumbuf[g * 256 + t] / fmaxf((float)cnt, 1.0f);
    float mx = __int_as_float(maxbuf[g * 256 + t]);
    if (cnt == 0) { mean = 0.f; mx = 0.f; }
    gfeat[g * 512 + t] = mean;
    gfeat[g * 512 + 256 + t] = mx;
}

// ---------------- MLP ----------------
__global__ void k_mlp(const float* __restrict__ in, const float* __restrict__ W,
                      const float* __restrict__ b, float* __restrict__ out, int Kdim, int Ndim,
                      int do_relu) {
    extern __shared__ float row[];
    int g = blockIdx.x, t = threadIdx.x;
    for (int k = t; k < Kdim; k += blockDim.x) row[k] = in[(size_t)g * Kdim + k];
    __syncthreads();
    if (t < Ndim) {
        float acc = b[t];
        for (int k = 0; k < Kdim; ++k) acc += row[k] * W[(size_t)k * Ndim + t];
        if (do_relu) acc = fmaxf(acc, 0.f);
        out[(size_t)g * Ndim + t] = acc;
    }
}

extern "C" void kernel_launch(void* const* d_in, const int* in_sizes, int n_in, void* d_out,
                              int out_size, void* d_ws, size_t ws_size, hipStream_t stream) {
    const float* x = (const float*)d_in[0];
    const int* eidx = (const int*)d_in[1];
    const int* batch = (const int*)d_in[2];
    const float* W1 = (const float*)d_in[3];
    const float* b1 = (const float*)d_in[4];
    const float* W2 = (const float*)d_in[5];
    const float* b2 = (const float*)d_in[6];
    const float* W3 = (const float*)d_in[7];
    const float* b3 = (const float*)d_in[8];
    const float* Wc1 = (const float*)d_in[9];
    const float* bc1 = (const float*)d_in[10];
    const float* Wc2 = (const float*)d_in[11];
    const float* bc2 = (const float*)d_in[12];
    const float* Wc3 = (const float*)d_in[13];
    const float* bc3 = (const float*)d_in[14];
    float* out = (float*)d_out;

    const int N = in_sizes[2];
    const int E = in_sizes[1] / 2;
    const int G = out_size / 5;
    const int* src = eidx;
    const int* dst = eidx + E;

    char* p = (char*)d_ws;
    auto alloc = [&](size_t bytes) {
        void* r = (void*)p;
        p += (bytes + 255) & ~(size_t)255;
        return r;
    };
    float* dis = (float*)alloc((size_t)N * 4);
    int* degc = (int*)alloc((size_t)N * 4);
    int* row_ptr = (int*)alloc((size_t)(N + 1) * 4);
    int* fill = (int*)alloc((size_t)N * 4);
    const int nch = CDIV(N, 1024);
    int* csum = (int*)alloc((size_t)nch * 4);
    int* coff = (int*)alloc((size_t)nch * 4);
    int* esrc = (int*)alloc((size_t)E * 4);
    float* ecoef = (float*)alloc((size_t)E * 4);
    float* sumbuf = (float*)alloc((size_t)G * 256 * 4);
    int* maxbuf = (int*)alloc((size_t)G * 256 * 4);
    float* gfeat = (float*)alloc((size_t)G * 512 * 4);
    float* g1 = (float*)alloc((size_t)G * 512 * 4);
    float* g2 = (float*)alloc((size_t)G * 256 * 4);
    ushort* Ahi = (ushort*)alloc((size_t)N * 256 * 2);
    ushort* Alo = (ushort*)alloc((size_t)N * 256 * 2);
    ushort* W1hi = (ushort*)alloc((size_t)128 * 256 * 2);
    ushort* W1lo = (ushort*)alloc((size_t)128 * 256 * 2);
    ushort* W2hi = (ushort*)alloc((size_t)256 * 256 * 2);
    ushort* W2lo = (ushort*)alloc((size_t)256 * 256 * 2);
    ushort* W3hi = (ushort*)alloc((size_t)256 * 256 * 2);
    ushort* W3lo = (ushort*)alloc((size_t)256 * 256 * 2);
    float* buf0 = (float*)alloc((size_t)N * 256 * 4);
    (void)ws_size;

    k_init<<<CDIV(N, 256), 256, 0, stream>>>(degc, N, sumbuf, maxbuf, G * 256);

    k_wsplit<<<CDIV(128 * 256, 256), 256, 0, stream>>>(W1, 128, W1hi, W1lo);
    k_wsplit<<<CDIV(256 * 256, 256), 256, 0, stream>>>(W2, 256, W2hi, W2lo);
    k_wsplit<<<CDIV(256 * 256, 256), 256, 0, stream>>>(W3, 256, W3hi, W3lo);

    k_deg<<<CDIV(E, 256), 256, 0, stream>>>(dst, E, degc);
    k_scan_partial<<<nch, 256, 0, stream>>>(degc, N, csum);
    k_scan_chunks<<<1, 64, 0, stream>>>(csum, nch, coff, row_ptr, N, E);
    k_scan_final<<<nch, 256, 0, stream>>>(degc, N, coff, row_ptr, fill, dis);
    k_fill<<<CDIV(E, 256), 256, 0, stream>>>(src, dst, E, row_ptr, fill, dis, esrc, ecoef);

    dim3 ggrid(CDIV(N, 128), 2);

    // layer 1
    k_agg<128><<<CDIV(N * 64, 256), 256, 0, stream>>>(x, dis, row_ptr, esrc, ecoef, N, Ahi, Alo);
    k_gemm_bf16<128, false><<<ggrid, 256, 0, stream>>>(Ahi, Alo, W1hi, W1lo, b1, N, buf0, 1,
                                                       batch, sumbuf, maxbuf);
    // layer 2
    k_agg<256><<<CDIV(N * 64, 256), 256, 0, stream>>>(buf0, dis, row_ptr, esrc, ecoef, N, Ahi, Alo);
    k_gemm_bf16<256, false><<<ggrid, 256, 0, stream>>>(Ahi, Alo, W2hi, W2lo, b2, N, buf0, 1,
                                                       batch, sumbuf, maxbuf);
    // layer 3: GEMM with fused pooling
    k_agg<256><<<CDIV(N * 64, 256), 256, 0, stream>>>(buf0, dis, row_ptr, esrc, ecoef, N, Ahi, Alo);
    k_gemm_bf16<256, true><<<ggrid, 256, 0, stream>>>(Ahi, Alo, W3hi, W3lo, b3, N, buf0, 1,
                                                      batch, sumbuf, maxbuf);

    k_pool_final<<<G, 256, 0, stream>>>(sumbuf, maxbuf, batch, N, gfeat);

    k_mlp<<<G, 512, 512 * 4, stream>>>(gfeat, Wc1, bc1, g1, 512, 512, 1);
    k_mlp<<<G, 256, 512 * 4, stream>>>(g1, Wc2, bc2, g2, 512, 256, 1);
    k_mlp<<<G, 64, 256 * 4, stream>>>(g2, Wc3, bc3, out, 256, 5, 0);
}

// Round 6
// 535.695 us; speedup vs baseline: 1.8238x; 1.2154x over previous
//
#include <hip/hip_runtime.h>
#include <cstdint>

#define CDIV(a, b) (((a) + (b) - 1) / (b))

typedef short bf16x8 __attribute__((ext_vector_type(8)));
typedef float f32x4 __attribute__((ext_vector_type(4)));

__device__ inline ushort f2bf_rn(float f) {
    uint32_t u = __float_as_uint(f);
    uint32_t rounding = 0x7FFF + ((u >> 16) & 1);
    return (ushort)((u + rounding) >> 16);
}
__device__ inline float bf2f(ushort h) { return __uint_as_float((uint32_t)h << 16); }

// ---------------- init: zero degc + sumbuf + maxbuf ----------------
__global__ void k_init(int* __restrict__ degc, int N, float* __restrict__ sumbuf,
                       int* __restrict__ maxbuf, int PB) {
    int i = blockIdx.x * blockDim.x + threadIdx.x;
    if (i < N) degc[i] = 0;
    if (i < PB) { sumbuf[i] = 0.f; maxbuf[i] = 0; }
}

// ---------------- degree ----------------
__global__ void k_deg(const int* __restrict__ dst, int E, int* __restrict__ degc) {
    int e = blockIdx.x * blockDim.x + threadIdx.x;
    if (e < E) atomicAdd(&degc[dst[e]], 1);
}

// ---------------- x -> bf16 hi plane (for layer-1 neighbor gather) ----------------
__global__ void k_xsplit(const float* __restrict__ x, int n, ushort* __restrict__ xhi) {
    int i = blockIdx.x * blockDim.x + threadIdx.x;
    if (i < n) xhi[i] = f2bf_rn(x[i]);
}

// ---------------- exclusive scan over degc -> row_ptr (+dis, +fill=0) ----------------
__global__ void k_scan_partial(const int* __restrict__ degc, int N, int* __restrict__ csum) {
    __shared__ int sm[256];
    int t = threadIdx.x;
    int idx = blockIdx.x * 1024 + t * 4;
    int s = 0;
#pragma unroll
    for (int j = 0; j < 4; ++j)
        if (idx + j < N) s += degc[idx + j];
    sm[t] = s;
    __syncthreads();
    for (int off = 128; off > 0; off >>= 1) {
        if (t < off) sm[t] += sm[t + off];
        __syncthreads();
    }
    if (t == 0) csum[blockIdx.x] = sm[0];
}

__global__ void k_scan_chunks(const int* __restrict__ csum, int nch, int* __restrict__ coff,
                              int* __restrict__ row_ptr, int N, int E) {
    if (threadIdx.x == 0 && blockIdx.x == 0) {
        int run = 0;
        for (int i = 0; i < nch; ++i) { coff[i] = run; run += csum[i]; }
        row_ptr[N] = E;
    }
}

__global__ void k_scan_final(const int* __restrict__ degc, int N, const int* __restrict__ coff,
                             int* __restrict__ row_ptr, int* __restrict__ fill,
                             float* __restrict__ dis) {
    __shared__ int sm[256];
    int t = threadIdx.x;
    int idx = blockIdx.x * 1024 + t * 4;
    int v[4];
    int s = 0;
#pragma unroll
    for (int j = 0; j < 4; ++j) {
        v[j] = (idx + j < N) ? degc[idx + j] : 0;
        s += v[j];
    }
    sm[t] = s;
    __syncthreads();
    for (int off = 1; off < 256; off <<= 1) {
        int x = (t >= off) ? sm[t - off] : 0;
        __syncthreads();
        sm[t] += x;
        __syncthreads();
    }
    int excl = sm[t] - s + coff[blockIdx.x];
#pragma unroll
    for (int j = 0; j < 4; ++j) {
        if (idx + j < N) {
            row_ptr[idx + j] = excl;
            fill[idx + j] = 0;
            dis[idx + j] = rsqrtf((float)v[j] + 1.0f);
            excl += v[j];
        }
    }
}

// ---------------- CSR fill ----------------
__global__ void k_fill(const int* __restrict__ src, const int* __restrict__ dst, int E,
                       const int* __restrict__ row_ptr, int* __restrict__ fill,
                       const float* __restrict__ dis, int* __restrict__ esrc,
                       float* __restrict__ ecoef) {
    int e = blockIdx.x * blockDim.x + threadIdx.x;
    if (e >= E) return;
    int d = dst[e], s = src[e];
    int pos = row_ptr[d] + atomicAdd(&fill[d], 1);
    esrc[pos] = s;
    ecoef[pos] = dis[s] * dis[d];
}

// ---------------- aggregation ----------------
// out[i] = dis_i^2 * self[i] + sum_e c_e * hhi[src_e]   (neighbors: bf16-hi only,
// halves per-XCD L2-miss streaming; self term full precision).
// SELF_F32: self from f32 xf (layer 1); else self = hhi+hlo (layers 2,3).
// Output split into bf16 hi/lo planes for the MFMA GEMM.
template <int C, bool SELF_F32>
__global__ __launch_bounds__(256) void k_agg(const float* __restrict__ xf,
                                             const ushort* __restrict__ hhi,
                                             const ushort* __restrict__ hlo,
                                             const float* __restrict__ dis,
                                             const int* __restrict__ row_ptr,
                                             const int* __restrict__ esrc,
                                             const float* __restrict__ ecoef, int N,
                                             ushort* __restrict__ ohi,
                                             ushort* __restrict__ olo) {
    constexpr int V = C / 64;
    int wave = (blockIdx.x * blockDim.x + threadIdx.x) >> 6;
    int lane = threadIdx.x & 63;
    if (wave >= N) return;
    const int i = wave;
    float di = dis[i];
    float dd = di * di;
    float acc[V];
    if constexpr (SELF_F32) {
        const float* xr = xf + (size_t)i * C + lane * V;
        if constexpr (V == 4) {
            float4 v = *reinterpret_cast<const float4*>(xr);
            acc[0] = dd * v.x; acc[1] = dd * v.y; acc[2] = dd * v.z; acc[3] = dd * v.w;
        } else {
            float2 v = *reinterpret_cast<const float2*>(xr);
            acc[0] = dd * v.x; acc[1] = dd * v.y;
        }
    } else {
        size_t sb = (size_t)i * C + lane * V;
        if constexpr (V == 4) {
            ushort4 h = *reinterpret_cast<const ushort4*>(hhi + sb);
            ushort4 l = *reinterpret_cast<const ushort4*>(hlo + sb);
            acc[0] = dd * (bf2f(h.x) + bf2f(l.x));
            acc[1] = dd * (bf2f(h.y) + bf2f(l.y));
            acc[2] = dd * (bf2f(h.z) + bf2f(l.z));
            acc[3] = dd * (bf2f(h.w) + bf2f(l.w));
        } else {
            ushort2 h = *reinterpret_cast<const ushort2*>(hhi + sb);
            ushort2 l = *reinterpret_cast<const ushort2*>(hlo + sb);
            acc[0] = dd * (bf2f(h.x) + bf2f(l.x));
            acc[1] = dd * (bf2f(h.y) + bf2f(l.y));
        }
    }
    int p0 = row_ptr[i], p1 = row_ptr[i + 1];
    int p = p0;
    if constexpr (V == 4) {
        for (; p + 4 <= p1; p += 4) {
            int s0 = esrc[p], s1 = esrc[p + 1], s2 = esrc[p + 2], s3 = esrc[p + 3];
            float c0 = ecoef[p], c1 = ecoef[p + 1], c2 = ecoef[p + 2], c3 = ecoef[p + 3];
            ushort4 v0 = *reinterpret_cast<const ushort4*>(hhi + (size_t)s0 * C + lane * V);
            ushort4 v1 = *reinterpret_cast<const ushort4*>(hhi + (size_t)s1 * C + lane * V);
            ushort4 v2 = *reinterpret_cast<const ushort4*>(hhi + (size_t)s2 * C + lane * V);
            ushort4 v3 = *reinterpret_cast<const ushort4*>(hhi + (size_t)s3 * C + lane * V);
            acc[0] += c0 * bf2f(v0.x); acc[1] += c0 * bf2f(v0.y);
            acc[2] += c0 * bf2f(v0.z); acc[3] += c0 * bf2f(v0.w);
            acc[0] += c1 * bf2f(v1.x); acc[1] += c1 * bf2f(v1.y);
            acc[2] += c1 * bf2f(v1.z); acc[3] += c1 * bf2f(v1.w);
            acc[0] += c2 * bf2f(v2.x); acc[1] += c2 * bf2f(v2.y);
            acc[2] += c2 * bf2f(v2.z); acc[3] += c2 * bf2f(v2.w);
            acc[0] += c3 * bf2f(v3.x); acc[1] += c3 * bf2f(v3.y);
            acc[2] += c3 * bf2f(v3.z); acc[3] += c3 * bf2f(v3.w);
        }
        for (; p < p1; ++p) {
            int s = esrc[p];
            float c = ecoef[p];
            ushort4 v = *reinterpret_cast<const ushort4*>(hhi + (size_t)s * C + lane * V);
            acc[0] += c * bf2f(v.x); acc[1] += c * bf2f(v.y);
            acc[2] += c * bf2f(v.z); acc[3] += c * bf2f(v.w);
        }
    } else {
        for (; p + 4 <= p1; p += 4) {
            int s0 = esrc[p], s1 = esrc[p + 1], s2 = esrc[p + 2], s3 = esrc[p + 3];
            float c0 = ecoef[p], c1 = ecoef[p + 1], c2 = ecoef[p + 2], c3 = ecoef[p + 3];
            ushort2 v0 = *reinterpret_cast<const ushort2*>(hhi + (size_t)s0 * C + lane * V);
            ushort2 v1 = *reinterpret_cast<const ushort2*>(hhi + (size_t)s1 * C + lane * V);
            ushort2 v2 = *reinterpret_cast<const ushort2*>(hhi + (size_t)s2 * C + lane * V);
            ushort2 v3 = *reinterpret_cast<const ushort2*>(hhi + (size_t)s3 * C + lane * V);
            acc[0] += c0 * bf2f(v0.x); acc[1] += c0 * bf2f(v0.y);
            acc[0] += c1 * bf2f(v1.x); acc[1] += c1 * bf2f(v1.y);
            acc[0] += c2 * bf2f(v2.x); acc[1] += c2 * bf2f(v2.y);
            acc[0] += c3 * bf2f(v3.x); acc[1] += c3 * bf2f(v3.y);
        }
        for (; p < p1; ++p) {
            int s = esrc[p];
            float c = ecoef[p];
            ushort2 v = *reinterpret_cast<const ushort2*>(hhi + (size_t)s * C + lane * V);
            acc[0] += c * bf2f(v.x); acc[1] += c * bf2f(v.y);
        }
    }
    ushort hi[V], lo[V];
#pragma unroll
    for (int j = 0; j < V; ++j) {
        hi[j] = f2bf_rn(acc[j]);
        lo[j] = f2bf_rn(acc[j] - bf2f(hi[j]));
    }
    size_t ob = (size_t)i * C + lane * V;
    if constexpr (V == 4) {
        *reinterpret_cast<ushort4*>(ohi + ob) = make_ushort4(hi[0], hi[1], hi[2], hi[3]);
        *reinterpret_cast<ushort4*>(olo + ob) = make_ushort4(lo[0], lo[1], lo[2], lo[3]);
    } else {
        *reinterpret_cast<ushort2*>(ohi + ob) = make_ushort2(hi[0], hi[1]);
        *reinterpret_cast<ushort2*>(olo + ob) = make_ushort2(lo[0], lo[1]);
    }
}

// ---------------- W split + fragment swizzle ----------------
__global__ void k_wsplit(const float* __restrict__ W, int K, ushort* __restrict__ Whi,
                         ushort* __restrict__ Wlo) {
    int idx = blockIdx.x * 256 + threadIdx.x;
    if (idx >= K * 256) return;
    int k = idx >> 8, n = idx & 255;
    float v = W[idx];
    ushort hi = f2bf_rn(v);
    ushort lo = f2bf_rn(v - bf2f(hi));
    int ks = k >> 5, r = k & 31;
    int lane = (r >> 3) * 16 + (n & 15);
    int j = r & 7;
    size_t d = (((size_t)ks * 16 + (n >> 4)) * 64 + lane) * 8 + j;
    Whi[d] = hi;
    Wlo[d] = lo;
}

// ---------------- split-bf16 MFMA GEMM with LDS-staged B panel ----------------
// POOL=false: writes relu(A@W+bias) as bf16 hi/lo planes (Hhi/Hlo).
// POOL=true : fused per-graph sum/max pooling epilogue (no h write).
template <int K, bool POOL>
__global__ __launch_bounds__(256) void k_gemm_bf16(const ushort* __restrict__ Ahi,
                                                   const ushort* __restrict__ Alo,
                                                   const ushort* __restrict__ Whi,
                                                   const ushort* __restrict__ Wlo,
                                                   const float* __restrict__ bias, int M,
                                                   ushort* __restrict__ Hhi,
                                                   ushort* __restrict__ Hlo,
                                                   const int* __restrict__ batch,
                                                   float* __restrict__ sumbuf,
                                                   int* __restrict__ maxbuf) {
    __shared__ ushort Bs[2][2][8][512];  // [buf][hi/lo][nf][lane*8] = 32 KB
    const int t = threadIdx.x;
    const int w = t >> 6, lane = t & 63;
    const int bm = blockIdx.x * 128;
    const int bn = blockIdx.y * 128;
    const int rw = bm + w * 32;

    f32x4 acc[2][8] = {};

    int row0 = min(rw + (lane & 15), M - 1);
    int row1 = min(rw + 16 + (lane & 15), M - 1);
    const int kbase = (lane >> 4) * 8;
    const ushort* pa0h = Ahi + (size_t)row0 * K + kbase;
    const ushort* pa0l = Alo + (size_t)row0 * K + kbase;
    const ushort* pa1h = Ahi + (size_t)row1 * K + kbase;
    const ushort* pa1l = Alo + (size_t)row1 * K + kbase;
    const int nf0 = bn >> 4;
    constexpr int KS = K / 32;

    auto stageB = [&](int ks, int b) {
#pragma unroll
        for (int q = 0; q < 2; ++q) {
            int nf = (w << 1) | q;
            size_t widx = (((size_t)ks * 16 + nf0 + nf) * 64 + lane) * 8;
            bf16x8 vh = *reinterpret_cast<const bf16x8*>(Whi + widx);
            bf16x8 vl = *reinterpret_cast<const bf16x8*>(Wlo + widx);
            *reinterpret_cast<bf16x8*>(&Bs[b][0][nf][lane * 8]) = vh;
            *reinterpret_cast<bf16x8*>(&Bs[b][1][nf][lane * 8]) = vl;
        }
    };

    stageB(0, 0);
    int buf = 0;
    for (int ks = 0; ks < KS; ++ks) {
        __syncthreads();
        if (ks + 1 < KS) stageB(ks + 1, buf ^ 1);
        bf16x8 a0h = *reinterpret_cast<const bf16x8*>(pa0h + ks * 32);
        bf16x8 a0l = *reinterpret_cast<const bf16x8*>(pa0l + ks * 32);
        bf16x8 a1h = *reinterpret_cast<const bf16x8*>(pa1h + ks * 32);
        bf16x8 a1l = *reinterpret_cast<const bf16x8*>(pa1l + ks * 32);
#pragma unroll
        for (int nf = 0; nf < 8; ++nf) {
            bf16x8 bh = *reinterpret_cast<const bf16x8*>(&Bs[buf][0][nf][lane * 8]);
            bf16x8 bl = *reinterpret_cast<const bf16x8*>(&Bs[buf][1][nf][lane * 8]);
            acc[0][nf] = __builtin_amdgcn_mfma_f32_16x16x32_bf16(a0h, bh, acc[0][nf], 0, 0, 0);
            acc[0][nf] = __builtin_amdgcn_mfma_f32_16x16x32_bf16(a0h, bl, acc[0][nf], 0, 0, 0);
            acc[0][nf] = __builtin_amdgcn_mfma_f32_16x16x32_bf16(a0l, bh, acc[0][nf], 0, 0, 0);
            acc[1][nf] = __builtin_amdgcn_mfma_f32_16x16x32_bf16(a1h, bh, acc[1][nf], 0, 0, 0);
            acc[1][nf] = __builtin_amdgcn_mfma_f32_16x16x32_bf16(a1h, bl, acc[1][nf], 0, 0, 0);
            acc[1][nf] = __builtin_amdgcn_mfma_f32_16x16x32_bf16(a1l, bh, acc[1][nf], 0, 0, 0);
        }
        buf ^= 1;
    }

    const int colq = lane & 15;
    const int rowq = (lane >> 4) * 4;

    if constexpr (!POOL) {
#pragma unroll
        for (int m = 0; m < 2; ++m) {
#pragma unroll
            for (int nf = 0; nf < 8; ++nf) {
                int col = bn + nf * 16 + colq;
                float bia = bias[col];
#pragma unroll
                for (int r = 0; r < 4; ++r) {
                    int rr = rw + m * 16 + rowq + r;
                    if (rr < M) {
                        float v = fmaxf(acc[m][nf][r] + bia, 0.f);
                        ushort h = f2bf_rn(v);
                        ushort l = f2bf_rn(v - bf2f(h));
                        size_t oi = (size_t)rr * 256 + col;
                        Hhi[oi] = h;
                        Hlo[oi] = l;
                    }
                }
            }
        }
    } else {
        int r0 = min(rw + rowq, M - 1);
        int r7 = min(rw + 16 + rowq + 3, M - 1);
        int g0 = batch[r0];
        int g7 = batch[r7];
        int gfirst = __shfl(g0, 0);
        bool uni = __all(g0 == gfirst && g7 == gfirst);
        if (uni) {
#pragma unroll
            for (int nf = 0; nf < 8; ++nf) {
                int col = bn + nf * 16 + colq;
                float bia = bias[col];
                float s = 0.f, mx = 0.f;
#pragma unroll
                for (int m = 0; m < 2; ++m) {
#pragma unroll
                    for (int r = 0; r < 4; ++r) {
                        int rr = rw + m * 16 + rowq + r;
                        float v = fmaxf(acc[m][nf][r] + bia, 0.f);
                        if (rr < M) { s += v; mx = fmaxf(mx, v); }
                    }
                }
                s += __shfl_xor(s, 16);
                mx = fmaxf(mx, __shfl_xor(mx, 16));
                s += __shfl_xor(s, 32);
                mx = fmaxf(mx, __shfl_xor(mx, 32));
                if ((lane >> 4) == 0) {
                    atomicAdd(&sumbuf[gfirst * 256 + col], s);
                    atomicMax(&maxbuf[gfirst * 256 + col], __float_as_int(mx));
                }
            }
        } else {
#pragma unroll
            for (int nf = 0; nf < 8; ++nf) {
                int col = bn + nf * 16 + colq;
                float bia = bias[col];
#pragma unroll
                for (int m = 0; m < 2; ++m) {
#pragma unroll
                    for (int r = 0; r < 4; ++r) {
                        int rr = rw + m * 16 + rowq + r;
                        if (rr < M) {
                            float v = fmaxf(acc[m][nf][r] + bia, 0.f);
                            int g = batch[rr];
                            atomicAdd(&sumbuf[g * 256 + col], v);
                            atomicMax(&maxbuf[g * 256 + col], __float_as_int(v));
                        }
                    }
                }
            }
        }
    }
}

// ---------------- pool finalize ----------------
__global__ __launch_bounds__(256) void k_pool_final(const float* __restrict__ sumbuf,
                                                    const int* __restrict__ maxbuf,
                                                    const int* __restrict__ batch, int N,
                                                    float* __restrict__ gfeat) {
    int g = blockIdx.x;
    int t = threadIdx.x;
    int lo = 0, hi = N;
    while (lo < hi) { int mid = (lo + hi) >> 1; if (batch[mid] < g) lo = mid + 1; else hi = mid; }
    int s = lo;
    lo = 0; hi = N;
    while (lo < hi) { int mid = (lo + hi) >> 1; if (batch[mid] < g + 1) lo = mid + 1; else hi = mid; }
    int cnt = lo - s;
    float mean = sumbuf[g * 256 + t] / fmaxf((float)cnt, 1.0f);
    float mx = __int_as_float(maxbuf[g * 256 + t]);
    if (cnt == 0) { mean = 0.f; mx = 0.f; }
    gfeat[g * 512 + t] = mean;
    gfeat[g * 512 + 256 + t] = mx;
}

// ---------------- MLP ----------------
__global__ void k_mlp(const float* __restrict__ in, const float* __restrict__ W,
                      const float* __restrict__ b, float* __restrict__ out, int Kdim, int Ndim,
                      int do_relu) {
    extern __shared__ float row[];
    int g = blockIdx.x, t = threadIdx.x;
    for (int k = t; k < Kdim; k += blockDim.x) row[k] = in[(size_t)g * Kdim + k];
    __syncthreads();
    if (t < Ndim) {
        float acc = b[t];
        for (int k = 0; k < Kdim; ++k) acc += row[k] * W[(size_t)k * Ndim + t];
        if (do_relu) acc = fmaxf(acc, 0.f);
        out[(size_t)g * Ndim + t] = acc;
    }
}

extern "C" void kernel_launch(void* const* d_in, const int* in_sizes, int n_in, void* d_out,
                              int out_size, void* d_ws, size_t ws_size, hipStream_t stream) {
    const float* x = (const float*)d_in[0];
    const int* eidx = (const int*)d_in[1];
    const int* batch = (const int*)d_in[2];
    const float* W1 = (const float*)d_in[3];
    const float* b1 = (const float*)d_in[4];
    const float* W2 = (const float*)d_in[5];
    const float* b2 = (const float*)d_in[6];
    const float* W3 = (const float*)d_in[7];
    const float* b3 = (const float*)d_in[8];
    const float* Wc1 = (const float*)d_in[9];
    const float* bc1 = (const float*)d_in[10];
    const float* Wc2 = (const float*)d_in[11];
    const float* bc2 = (const float*)d_in[12];
    const float* Wc3 = (const float*)d_in[13];
    const float* bc3 = (const float*)d_in[14];
    float* out = (float*)d_out;

    const int N = in_sizes[2];
    const int E = in_sizes[1] / 2;
    const int G = out_size / 5;
    const int* src = eidx;
    const int* dst = eidx + E;

    char* p = (char*)d_ws;
    auto alloc = [&](size_t bytes) {
        void* r = (void*)p;
        p += (bytes + 255) & ~(size_t)255;
        return r;
    };
    float* dis = (float*)alloc((size_t)N * 4);
    int* degc = (int*)alloc((size_t)N * 4);
    int* row_ptr = (int*)alloc((size_t)(N + 1) * 4);
    int* fill = (int*)alloc((size_t)N * 4);
    const int nch = CDIV(N, 1024);
    int* csum = (int*)alloc((size_t)nch * 4);
    int* coff = (int*)alloc((size_t)nch * 4);
    int* esrc = (int*)alloc((size_t)E * 4);
    float* ecoef = (float*)alloc((size_t)E * 4);
    float* sumbuf = (float*)alloc((size_t)G * 256 * 4);
    int* maxbuf = (int*)alloc((size_t)G * 256 * 4);
    float* gfeat = (float*)alloc((size_t)G * 512 * 4);
    float* g1 = (float*)alloc((size_t)G * 512 * 4);
    float* g2 = (float*)alloc((size_t)G * 256 * 4);
    ushort* Ahi = (ushort*)alloc((size_t)N * 256 * 2);
    ushort* Alo = (ushort*)alloc((size_t)N * 256 * 2);
    ushort* Hhi = (ushort*)alloc((size_t)N * 256 * 2);
    ushort* Hlo = (ushort*)alloc((size_t)N * 256 * 2);
    ushort* Xhi = (ushort*)alloc((size_t)N * 128 * 2);
    ushort* W1hi = (ushort*)alloc((size_t)128 * 256 * 2);
    ushort* W1lo = (ushort*)alloc((size_t)128 * 256 * 2);
    ushort* W2hi = (ushort*)alloc((size_t)256 * 256 * 2);
    ushort* W2lo = (ushort*)alloc((size_t)256 * 256 * 2);
    ushort* W3hi = (ushort*)alloc((size_t)256 * 256 * 2);
    ushort* W3lo = (ushort*)alloc((size_t)256 * 256 * 2);
    (void)ws_size;

    k_init<<<CDIV(N, 256), 256, 0, stream>>>(degc, N, sumbuf, maxbuf, G * 256);

    k_wsplit<<<CDIV(128 * 256, 256), 256, 0, stream>>>(W1, 128, W1hi, W1lo);
    k_wsplit<<<CDIV(256 * 256, 256), 256, 0, stream>>>(W2, 256, W2hi, W2lo);
    k_wsplit<<<CDIV(256 * 256, 256), 256, 0, stream>>>(W3, 256, W3hi, W3lo);
    k_xsplit<<<CDIV(N * 128, 256), 256, 0, stream>>>(x, N * 128, Xhi);

    k_deg<<<CDIV(E, 256), 256, 0, stream>>>(dst, E, degc);
    k_scan_partial<<<nch, 256, 0, stream>>>(degc, N, csum);
    k_scan_chunks<<<1, 64, 0, stream>>>(csum, nch, coff, row_ptr, N, E);
    k_scan_final<<<nch, 256, 0, stream>>>(degc, N, coff, row_ptr, fill, dis);
    k_fill<<<CDIV(E, 256), 256, 0, stream>>>(src, dst, E, row_ptr, fill, dis, esrc, ecoef);

    dim3 ggrid(CDIV(N, 128), 2);

    // layer 1: self from f32 x, neighbors from Xhi
    k_agg<128, true><<<CDIV(N * 64, 256), 256, 0, stream>>>(x, Xhi, nullptr, dis, row_ptr,
                                                            esrc, ecoef, N, Ahi, Alo);
    k_gemm_bf16<128, false><<<ggrid, 256, 0, stream>>>(Ahi, Alo, W1hi, W1lo, b1, N, Hhi, Hlo,
                                                       batch, sumbuf, maxbuf);
    // layer 2: self from Hhi+Hlo, neighbors from Hhi
    k_agg<256, false><<<CDIV(N * 64, 256), 256, 0, stream>>>(nullptr, Hhi, Hlo, dis, row_ptr,
                                                             esrc, ecoef, N, Ahi, Alo);
    k_gemm_bf16<256, false><<<ggrid, 256, 0, stream>>>(Ahi, Alo, W2hi, W2lo, b2, N, Hhi, Hlo,
                                                       batch, sumbuf, maxbuf);
    // layer 3: agg + GEMM with fused pooling
    k_agg<256, false><<<CDIV(N * 64, 256), 256, 0, stream>>>(nullptr, Hhi, Hlo, dis, row_ptr,
                                                             esrc, ecoef, N, Ahi, Alo);
    k_gemm_bf16<256, true><<<ggrid, 256, 0, stream>>>(Ahi, Alo, W3hi, W3lo, b3, N, Hhi, Hlo,
                                                      batch, sumbuf, maxbuf);

    k_pool_final<<<G, 256, 0, stream>>>(sumbuf, maxbuf, batch, N, gfeat);

    k_mlp<<<G, 512, 512 * 4, stream>>>(gfeat, Wc1, bc1, g1, 512, 512, 1);
    k_mlp<<<G, 256, 512 * 4, stream>>>(g1, Wc2, bc2, g2, 512, 256, 1);
    k_mlp<<<G, 64, 256 * 4, stream>>>(g2, Wc3, bc3, out, 256, 5, 0);
}

// Round 7
// 505.545 us; speedup vs baseline: 1.9326x; 1.0596x over previous
//
#include <hip/hip_runtime.h>
#include <cstdint>

#define CDIV(a, b) (((a) + (b) - 1) / (b))

typedef short bf16x8 __attribute__((ext_vector_type(8)));
typedef float f32x4 __attribute__((ext_vector_type(4)));

__device__ inline ushort f2bf_rn(float f) {
    uint32_t u = __float_as_uint(f);
    uint32_t rounding = 0x7FFF + ((u >> 16) & 1);
    return (ushort)((u + rounding) >> 16);
}
__device__ inline float bf2f(ushort h) { return __uint_as_float((uint32_t)h << 16); }

// ---------------- init ----------------
__global__ void k_init(int* __restrict__ degc, int N, float* __restrict__ sumbuf,
                       int* __restrict__ maxbuf, int PB) {
    int i = blockIdx.x * blockDim.x + threadIdx.x;
    if (i < N) degc[i] = 0;
    if (i < PB) { sumbuf[i] = 0.f; maxbuf[i] = 0; }
}

// ---------------- degree ----------------
__global__ void k_deg(const int* __restrict__ dst, int E, int* __restrict__ degc) {
    int e = blockIdx.x * blockDim.x + threadIdx.x;
    if (e < E) atomicAdd(&degc[dst[e]], 1);
}

// ---------------- x -> bf16 hi plane ----------------
__global__ void k_xsplit(const float* __restrict__ x, int n, ushort* __restrict__ xhi) {
    int i = blockIdx.x * blockDim.x + threadIdx.x;
    if (i < n) xhi[i] = f2bf_rn(x[i]);
}

// ---------------- scan -> row_ptr (+dis, +fill=0) ----------------
__global__ void k_scan_partial(const int* __restrict__ degc, int N, int* __restrict__ csum) {
    __shared__ int sm[256];
    int t = threadIdx.x;
    int idx = blockIdx.x * 1024 + t * 4;
    int s = 0;
#pragma unroll
    for (int j = 0; j < 4; ++j)
        if (idx + j < N) s += degc[idx + j];
    sm[t] = s;
    __syncthreads();
    for (int off = 128; off > 0; off >>= 1) {
        if (t < off) sm[t] += sm[t + off];
        __syncthreads();
    }
    if (t == 0) csum[blockIdx.x] = sm[0];
}

__global__ void k_scan_chunks(const int* __restrict__ csum, int nch, int* __restrict__ coff,
                              int* __restrict__ row_ptr, int N, int E) {
    if (threadIdx.x == 0 && blockIdx.x == 0) {
        int run = 0;
        for (int i = 0; i < nch; ++i) { coff[i] = run; run += csum[i]; }
        row_ptr[N] = E;
    }
}

__global__ void k_scan_final(const int* __restrict__ degc, int N, const int* __restrict__ coff,
                             int* __restrict__ row_ptr, int* __restrict__ fill,
                             float* __restrict__ dis) {
    __shared__ int sm[256];
    int t = threadIdx.x;
    int idx = blockIdx.x * 1024 + t * 4;
    int v[4];
    int s = 0;
#pragma unroll
    for (int j = 0; j < 4; ++j) {
        v[j] = (idx + j < N) ? degc[idx + j] : 0;
        s += v[j];
    }
    sm[t] = s;
    __syncthreads();
    for (int off = 1; off < 256; off <<= 1) {
        int x = (t >= off) ? sm[t - off] : 0;
        __syncthreads();
        sm[t] += x;
        __syncthreads();
    }
    int excl = sm[t] - s + coff[blockIdx.x];
#pragma unroll
    for (int j = 0; j < 4; ++j) {
        if (idx + j < N) {
            row_ptr[idx + j] = excl;
            fill[idx + j] = 0;
            dis[idx + j] = rsqrtf((float)v[j] + 1.0f);
            excl += v[j];
        }
    }
}

// ---------------- CSR fill ----------------
__global__ void k_fill(const int* __restrict__ src, const int* __restrict__ dst, int E,
                       const int* __restrict__ row_ptr, int* __restrict__ fill,
                       const float* __restrict__ dis, int* __restrict__ esrc,
                       float* __restrict__ ecoef) {
    int e = blockIdx.x * blockDim.x + threadIdx.x;
    if (e >= E) return;
    int d = dst[e], s = src[e];
    int pos = row_ptr[d] + atomicAdd(&fill[d], 1);
    esrc[pos] = s;
    ecoef[pos] = dis[s] * dis[d];
}

// ---------------- aggregation (bf16-hi neighbor gather) ----------------
template <int C, bool SELF_F32>
__global__ __launch_bounds__(256) void k_agg(const float* __restrict__ xf,
                                             const ushort* __restrict__ hhi,
                                             const ushort* __restrict__ hlo,
                                             const float* __restrict__ dis,
                                             const int* __restrict__ row_ptr,
                                             const int* __restrict__ esrc,
                                             const float* __restrict__ ecoef, int N,
                                             ushort* __restrict__ ohi,
                                             ushort* __restrict__ olo) {
    constexpr int V = C / 64;
    int wave = (blockIdx.x * blockDim.x + threadIdx.x) >> 6;
    int lane = threadIdx.x & 63;
    if (wave >= N) return;
    const int i = wave;
    float di = dis[i];
    float dd = di * di;
    float acc[V];
    if constexpr (SELF_F32) {
        const float* xr = xf + (size_t)i * C + lane * V;
        if constexpr (V == 4) {
            float4 v = *reinterpret_cast<const float4*>(xr);
            acc[0] = dd * v.x; acc[1] = dd * v.y; acc[2] = dd * v.z; acc[3] = dd * v.w;
        } else {
            float2 v = *reinterpret_cast<const float2*>(xr);
            acc[0] = dd * v.x; acc[1] = dd * v.y;
        }
    } else {
        size_t sb = (size_t)i * C + lane * V;
        if constexpr (V == 4) {
            ushort4 h = *reinterpret_cast<const ushort4*>(hhi + sb);
            ushort4 l = *reinterpret_cast<const ushort4*>(hlo + sb);
            acc[0] = dd * (bf2f(h.x) + bf2f(l.x));
            acc[1] = dd * (bf2f(h.y) + bf2f(l.y));
            acc[2] = dd * (bf2f(h.z) + bf2f(l.z));
            acc[3] = dd * (bf2f(h.w) + bf2f(l.w));
        } else {
            ushort2 h = *reinterpret_cast<const ushort2*>(hhi + sb);
            ushort2 l = *reinterpret_cast<const ushort2*>(hlo + sb);
            acc[0] = dd * (bf2f(h.x) + bf2f(l.x));
            acc[1] = dd * (bf2f(h.y) + bf2f(l.y));
        }
    }
    int p0 = row_ptr[i], p1 = row_ptr[i + 1];
    int p = p0;
    if constexpr (V == 4) {
        for (; p + 4 <= p1; p += 4) {
            int s0 = esrc[p], s1 = esrc[p + 1], s2 = esrc[p + 2], s3 = esrc[p + 3];
            float c0 = ecoef[p], c1 = ecoef[p + 1], c2 = ecoef[p + 2], c3 = ecoef[p + 3];
            ushort4 v0 = *reinterpret_cast<const ushort4*>(hhi + (size_t)s0 * C + lane * V);
            ushort4 v1 = *reinterpret_cast<const ushort4*>(hhi + (size_t)s1 * C + lane * V);
            ushort4 v2 = *reinterpret_cast<const ushort4*>(hhi + (size_t)s2 * C + lane * V);
            ushort4 v3 = *reinterpret_cast<const ushort4*>(hhi + (size_t)s3 * C + lane * V);
            acc[0] += c0 * bf2f(v0.x); acc[1] += c0 * bf2f(v0.y);
            acc[2] += c0 * bf2f(v0.z); acc[3] += c0 * bf2f(v0.w);
            acc[0] += c1 * bf2f(v1.x); acc[1] += c1 * bf2f(v1.y);
            acc[2] += c1 * bf2f(v1.z); acc[3] += c1 * bf2f(v1.w);
            acc[0] += c2 * bf2f(v2.x); acc[1] += c2 * bf2f(v2.y);
            acc[2] += c2 * bf2f(v2.z); acc[3] += c2 * bf2f(v2.w);
            acc[0] += c3 * bf2f(v3.x); acc[1] += c3 * bf2f(v3.y);
            acc[2] += c3 * bf2f(v3.z); acc[3] += c3 * bf2f(v3.w);
        }
        for (; p < p1; ++p) {
            int s = esrc[p];
            float c = ecoef[p];
            ushort4 v = *reinterpret_cast<const ushort4*>(hhi + (size_t)s * C + lane * V);
            acc[0] += c * bf2f(v.x); acc[1] += c * bf2f(v.y);
            acc[2] += c * bf2f(v.z); acc[3] += c * bf2f(v.w);
        }
    } else {
        for (; p + 4 <= p1; p += 4) {
            int s0 = esrc[p], s1 = esrc[p + 1], s2 = esrc[p + 2], s3 = esrc[p + 3];
            float c0 = ecoef[p], c1 = ecoef[p + 1], c2 = ecoef[p + 2], c3 = ecoef[p + 3];
            ushort2 v0 = *reinterpret_cast<const ushort2*>(hhi + (size_t)s0 * C + lane * V);
            ushort2 v1 = *reinterpret_cast<const ushort2*>(hhi + (size_t)s1 * C + lane * V);
            ushort2 v2 = *reinterpret_cast<const ushort2*>(hhi + (size_t)s2 * C + lane * V);
            ushort2 v3 = *reinterpret_cast<const ushort2*>(hhi + (size_t)s3 * C + lane * V);
            acc[0] += c0 * bf2f(v0.x); acc[1] += c0 * bf2f(v0.y);
            acc[0] += c1 * bf2f(v1.x); acc[1] += c1 * bf2f(v1.y);
            acc[0] += c2 * bf2f(v2.x); acc[1] += c2 * bf2f(v2.y);
            acc[0] += c3 * bf2f(v3.x); acc[1] += c3 * bf2f(v3.y);
        }
        for (; p < p1; ++p) {
            int s = esrc[p];
            float c = ecoef[p];
            ushort2 v = *reinterpret_cast<const ushort2*>(hhi + (size_t)s * C + lane * V);
            acc[0] += c * bf2f(v.x); acc[1] += c * bf2f(v.y);
        }
    }
    ushort hi[V], lo[V];
#pragma unroll
    for (int j = 0; j < V; ++j) {
        hi[j] = f2bf_rn(acc[j]);
        lo[j] = f2bf_rn(acc[j] - bf2f(hi[j]));
    }
    size_t ob = (size_t)i * C + lane * V;
    if constexpr (V == 4) {
        *reinterpret_cast<ushort4*>(ohi + ob) = make_ushort4(hi[0], hi[1], hi[2], hi[3]);
        *reinterpret_cast<ushort4*>(olo + ob) = make_ushort4(lo[0], lo[1], lo[2], lo[3]);
    } else {
        *reinterpret_cast<ushort2*>(ohi + ob) = make_ushort2(hi[0], hi[1]);
        *reinterpret_cast<ushort2*>(olo + ob) = make_ushort2(lo[0], lo[1]);
    }
}

// ---------------- W split + fragment swizzle ----------------
__global__ void k_wsplit(const float* __restrict__ W, int K, ushort* __restrict__ Whi,
                         ushort* __restrict__ Wlo) {
    int idx = blockIdx.x * 256 + threadIdx.x;
    if (idx >= K * 256) return;
    int k = idx >> 8, n = idx & 255;
    float v = W[idx];
    ushort hi = f2bf_rn(v);
    ushort lo = f2bf_rn(v - bf2f(hi));
    int ks = k >> 5, r = k & 31;
    int lane = (r >> 3) * 16 + (n & 15);
    int j = r & 7;
    size_t d = (((size_t)ks * 16 + (n >> 4)) * 64 + lane) * 8 + j;
    Whi[d] = hi;
    Wlo[d] = lo;
}

// ---------------- pipelined split-bf16 MFMA GEMM ----------------
// Software pipeline (T14): B panel global->REG issued ~2 k-steps early,
// REG->LDS write after the MFMAs; A fragments register-prefetched 1 k-step
// ahead. 1-D grid with bijective XCD-chunked swizzle so the two BN-halves
// sharing an A panel land on the same XCD L2.
template <int K, bool POOL>
__global__ __launch_bounds__(256) void k_gemm_bf16(const ushort* __restrict__ Ahi,
                                                   const ushort* __restrict__ Alo,
                                                   const ushort* __restrict__ Whi,
                                                   const ushort* __restrict__ Wlo,
                                                   const float* __restrict__ bias, int M,
                                                   ushort* __restrict__ Hhi,
                                                   ushort* __restrict__ Hlo,
                                                   const int* __restrict__ batch,
                                                   float* __restrict__ sumbuf,
                                                   int* __restrict__ maxbuf) {
    __shared__ ushort Bs[2][2][8][512];  // [buf][hi/lo][nf][lane*8] = 32 KB
    const int t = threadIdx.x;
    const int w = t >> 6, lane = t & 63;

    // bijective XCD-chunked swizzle (m204)
    const int nwg = (int)gridDim.x;
    const int orig = (int)blockIdx.x;
    const int q = nwg >> 3, r = nwg & 7;
    const int xcd = orig & 7;
    const int swz = (xcd < r ? xcd * (q + 1) : r * (q + 1) + (xcd - r) * q) + (orig >> 3);
    const int bm = (swz >> 1) * 128;
    const int bn = (swz & 1) * 128;
    const int rw = bm + w * 32;

    f32x4 acc[2][8] = {};

    int row0 = min(rw + (lane & 15), M - 1);
    int row1 = min(rw + 16 + (lane & 15), M - 1);
    const int kbase = (lane >> 4) * 8;
    const ushort* pa0h = Ahi + (size_t)row0 * K + kbase;
    const ushort* pa0l = Alo + (size_t)row0 * K + kbase;
    const ushort* pa1h = Ahi + (size_t)row1 * K + kbase;
    const ushort* pa1l = Alo + (size_t)row1 * K + kbase;
    const int nf0 = bn >> 4;
    constexpr int KS = K / 32;

    bf16x8 sbh[2], sbl[2];  // stage regs (wave's 2 n-frags)
    auto loadB = [&](int ks) {
#pragma unroll
        for (int q2 = 0; q2 < 2; ++q2) {
            int nf = (w << 1) | q2;
            size_t widx = (((size_t)ks * 16 + nf0 + nf) * 64 + lane) * 8;
            sbh[q2] = *reinterpret_cast<const bf16x8*>(Whi + widx);
            sbl[q2] = *reinterpret_cast<const bf16x8*>(Wlo + widx);
        }
    };
    auto writeB = [&](int b) {
#pragma unroll
        for (int q2 = 0; q2 < 2; ++q2) {
            int nf = (w << 1) | q2;
            *reinterpret_cast<bf16x8*>(&Bs[b][0][nf][lane * 8]) = sbh[q2];
            *reinterpret_cast<bf16x8*>(&Bs[b][1][nf][lane * 8]) = sbl[q2];
        }
    };

    bf16x8 c0h, c0l, c1h, c1l, n0h, n0l, n1h, n1l;
    auto loadA = [&](int ks, bf16x8& x0h, bf16x8& x0l, bf16x8& x1h, bf16x8& x1l) {
        x0h = *reinterpret_cast<const bf16x8*>(pa0h + ks * 32);
        x0l = *reinterpret_cast<const bf16x8*>(pa0l + ks * 32);
        x1h = *reinterpret_cast<const bf16x8*>(pa1h + ks * 32);
        x1l = *reinterpret_cast<const bf16x8*>(pa1l + ks * 32);
    };

    // prologue
    loadB(0);
    writeB(0);               // vmcnt drain once, prologue only
    loadA(0, c0h, c0l, c1h, c1l);
    if (KS > 1) loadB(1);    // in flight across the first MFMA phase
    __syncthreads();

#pragma unroll
    for (int ks = 0; ks < KS; ++ks) {
        const int buf = ks & 1;
        if (ks + 1 < KS) loadA(ks + 1, n0h, n0l, n1h, n1l);  // issue early
#pragma unroll
        for (int nf = 0; nf < 8; ++nf) {
            bf16x8 bh = *reinterpret_cast<const bf16x8*>(&Bs[buf][0][nf][lane * 8]);
            bf16x8 bl = *reinterpret_cast<const bf16x8*>(&Bs[buf][1][nf][lane * 8]);
            acc[0][nf] = __builtin_amdgcn_mfma_f32_16x16x32_bf16(c0h, bh, acc[0][nf], 0, 0, 0);
            acc[0][nf] = __builtin_amdgcn_mfma_f32_16x16x32_bf16(c0h, bl, acc[0][nf], 0, 0, 0);
            acc[0][nf] = __builtin_amdgcn_mfma_f32_16x16x32_bf16(c0l, bh, acc[0][nf], 0, 0, 0);
            acc[1][nf] = __builtin_amdgcn_mfma_f32_16x16x32_bf16(c1h, bh, acc[1][nf], 0, 0, 0);
            acc[1][nf] = __builtin_amdgcn_mfma_f32_16x16x32_bf16(c1h, bl, acc[1][nf], 0, 0, 0);
            acc[1][nf] = __builtin_amdgcn_mfma_f32_16x16x32_bf16(c1l, bh, acc[1][nf], 0, 0, 0);
        }
        if (ks + 1 < KS) {
            writeB(buf ^ 1);                  // waits only on loadB(ks+1)'s vmcnt
            if (ks + 2 < KS) loadB(ks + 2);   // issue next stage early
            __syncthreads();
            c0h = n0h; c0l = n0l; c1h = n1h; c1l = n1l;
        }
    }

    const int colq = lane & 15;
    const int rowq = (lane >> 4) * 4;

    if constexpr (!POOL) {
#pragma unroll
        for (int m = 0; m < 2; ++m) {
#pragma unroll
            for (int nf = 0; nf < 8; ++nf) {
                int col = bn + nf * 16 + colq;
                float bia = bias[col];
#pragma unroll
                for (int r2 = 0; r2 < 4; ++r2) {
                    int rr = rw + m * 16 + rowq + r2;
                    if (rr < M) {
                        float v = fmaxf(acc[m][nf][r2] + bia, 0.f);
                        ushort h = f2bf_rn(v);
                        ushort l = f2bf_rn(v - bf2f(h));
                        size_t oi = (size_t)rr * 256 + col;
                        Hhi[oi] = h;
                        Hlo[oi] = l;
                    }
                }
            }
        }
    } else {
        int r0 = min(rw + rowq, M - 1);
        int r7 = min(rw + 16 + rowq + 3, M - 1);
        int g0 = batch[r0];
        int g7 = batch[r7];
        int gfirst = __shfl(g0, 0);
        bool uni = __all(g0 == gfirst && g7 == gfirst);
        if (uni) {
#pragma unroll
            for (int nf = 0; nf < 8; ++nf) {
                int col = bn + nf * 16 + colq;
                float bia = bias[col];
                float s = 0.f, mx = 0.f;
#pragma unroll
                for (int m = 0; m < 2; ++m) {
#pragma unroll
                    for (int r2 = 0; r2 < 4; ++r2) {
                        int rr = rw + m * 16 + rowq + r2;
                        float v = fmaxf(acc[m][nf][r2] + bia, 0.f);
                        if (rr < M) { s += v; mx = fmaxf(mx, v); }
                    }
                }
                s += __shfl_xor(s, 16);
                mx = fmaxf(mx, __shfl_xor(mx, 16));
                s += __shfl_xor(s, 32);
                mx = fmaxf(mx, __shfl_xor(mx, 32));
                if ((lane >> 4) == 0) {
                    atomicAdd(&sumbuf[gfirst * 256 + col], s);
                    atomicMax(&maxbuf[gfirst * 256 + col], __float_as_int(mx));
                }
            }
        } else {
#pragma unroll
            for (int nf = 0; nf < 8; ++nf) {
                int col = bn + nf * 16 + colq;
                float bia = bias[col];
#pragma unroll
                for (int m = 0; m < 2; ++m) {
#pragma unroll
                    for (int r2 = 0; r2 < 4; ++r2) {
                        int rr = rw + m * 16 + rowq + r2;
                        if (rr < M) {
                            float v = fmaxf(acc[m][nf][r2] + bia, 0.f);
                            int g = batch[rr];
                            atomicAdd(&sumbuf[g * 256 + col], v);
                            atomicMax(&maxbuf[g * 256 + col], __float_as_int(v));
                        }
                    }
                }
            }
        }
    }
}

// ---------------- pool finalize ----------------
__global__ __launch_bounds__(256) void k_pool_final(const float* __restrict__ sumbuf,
                                                    const int* __restrict__ maxbuf,
                                                    const int* __restrict__ batch, int N,
                                                    float* __restrict__ gfeat) {
    int g = blockIdx.x;
    int t = threadIdx.x;
    int lo = 0, hi = N;
    while (lo < hi) { int mid = (lo + hi) >> 1; if (batch[mid] < g) lo = mid + 1; else hi = mid; }
    int s = lo;
    lo = 0; hi = N;
    while (lo < hi) { int mid = (lo + hi) >> 1; if (batch[mid] < g + 1) lo = mid + 1; else hi = mid; }
    int cnt = lo - s;
    float mean = sumbuf[g * 256 + t] / fmaxf((float)cnt, 1.0f);
    float mx = __int_as_float(maxbuf[g * 256 + t]);
    if (cnt == 0) { mean = 0.f; mx = 0.f; }
    gfeat[g * 512 + t] = mean;
    gfeat[g * 512 + 256 + t] = mx;
}

// ---------------- MLP ----------------
__global__ void k_mlp(const float* __restrict__ in, const float* __restrict__ W,
                      const float* __restrict__ b, float* __restrict__ out, int Kdim, int Ndim,
                      int do_relu) {
    extern __shared__ float row[];
    int g = blockIdx.x, t = threadIdx.x;
    for (int k = t; k < Kdim; k += blockDim.x) row[k] = in[(size_t)g * Kdim + k];
    __syncthreads();
    if (t < Ndim) {
        float acc = b[t];
        for (int k = 0; k < Kdim; ++k) acc += row[k] * W[(size_t)k * Ndim + t];
        if (do_relu) acc = fmaxf(acc, 0.f);
        out[(size_t)g * Ndim + t] = acc;
    }
}

extern "C" void kernel_launch(void* const* d_in, const int* in_sizes, int n_in, void* d_out,
                              int out_size, void* d_ws, size_t ws_size, hipStream_t stream) {
    const float* x = (const float*)d_in[0];
    const int* eidx = (const int*)d_in[1];
    const int* batch = (const int*)d_in[2];
    const float* W1 = (const float*)d_in[3];
    const float* b1 = (const float*)d_in[4];
    const float* W2 = (const float*)d_in[5];
    const float* b2 = (const float*)d_in[6];
    const float* W3 = (const float*)d_in[7];
    const float* b3 = (const float*)d_in[8];
    const float* Wc1 = (const float*)d_in[9];
    const float* bc1 = (const float*)d_in[10];
    const float* Wc2 = (const float*)d_in[11];
    const float* bc2 = (const float*)d_in[12];
    const float* Wc3 = (const float*)d_in[13];
    const float* bc3 = (const float*)d_in[14];
    float* out = (float*)d_out;

    const int N = in_sizes[2];
    const int E = in_sizes[1] / 2;
    const int G = out_size / 5;
    const int* src = eidx;
    const int* dst = eidx + E;

    char* p = (char*)d_ws;
    auto alloc = [&](size_t bytes) {
        void* r = (void*)p;
        p += (bytes + 255) & ~(size_t)255;
        return r;
    };
    float* dis = (float*)alloc((size_t)N * 4);
    int* degc = (int*)alloc((size_t)N * 4);
    int* row_ptr = (int*)alloc((size_t)(N + 1) * 4);
    int* fill = (int*)alloc((size_t)N * 4);
    const int nch = CDIV(N, 1024);
    int* csum = (int*)alloc((size_t)nch * 4);
    int* coff = (int*)alloc((size_t)nch * 4);
    int* esrc = (int*)alloc((size_t)E * 4);
    float* ecoef = (float*)alloc((size_t)E * 4);
    float* sumbuf = (float*)alloc((size_t)G * 256 * 4);
    int* maxbuf = (int*)alloc((size_t)G * 256 * 4);
    float* gfeat = (float*)alloc((size_t)G * 512 * 4);
    float* g1 = (float*)alloc((size_t)G * 512 * 4);
    float* g2 = (float*)alloc((size_t)G * 256 * 4);
    ushort* Ahi = (ushort*)alloc((size_t)N * 256 * 2);
    ushort* Alo = (ushort*)alloc((size_t)N * 256 * 2);
    ushort* Hhi = (ushort*)alloc((size_t)N * 256 * 2);
    ushort* Hlo = (ushort*)alloc((size_t)N * 256 * 2);
    ushort* Xhi = (ushort*)alloc((size_t)N * 128 * 2);
    ushort* W1hi = (ushort*)alloc((size_t)128 * 256 * 2);
    ushort* W1lo = (ushort*)alloc((size_t)128 * 256 * 2);
    ushort* W2hi = (ushort*)alloc((size_t)256 * 256 * 2);
    ushort* W2lo = (ushort*)alloc((size_t)256 * 256 * 2);
    ushort* W3hi = (ushort*)alloc((size_t)256 * 256 * 2);
    ushort* W3lo = (ushort*)alloc((size_t)256 * 256 * 2);
    (void)ws_size;

    k_init<<<CDIV(N, 256), 256, 0, stream>>>(degc, N, sumbuf, maxbuf, G * 256);

    k_wsplit<<<CDIV(128 * 256, 256), 256, 0, stream>>>(W1, 128, W1hi, W1lo);
    k_wsplit<<<CDIV(256 * 256, 256), 256, 0, stream>>>(W2, 256, W2hi, W2lo);
    k_wsplit<<<CDIV(256 * 256, 256), 256, 0, stream>>>(W3, 256, W3hi, W3lo);
    k_xsplit<<<CDIV(N * 128, 256), 256, 0, stream>>>(x, N * 128, Xhi);

    k_deg<<<CDIV(E, 256), 256, 0, stream>>>(dst, E, degc);
    k_scan_partial<<<nch, 256, 0, stream>>>(degc, N, csum);
    k_scan_chunks<<<1, 64, 0, stream>>>(csum, nch, coff, row_ptr, N, E);
    k_scan_final<<<nch, 256, 0, stream>>>(degc, N, coff, row_ptr, fill, dis);
    k_fill<<<CDIV(E, 256), 256, 0, stream>>>(src, dst, E, row_ptr, fill, dis, esrc, ecoef);

    const int ggrid = CDIV(N, 128) * 2;  // 1-D, swizzled in-kernel

    // layer 1
    k_agg<128, true><<<CDIV(N * 64, 256), 256, 0, stream>>>(x, Xhi, nullptr, dis, row_ptr,
                                                            esrc, ecoef, N, Ahi, Alo);
    k_gemm_bf16<128, false><<<ggrid, 256, 0, stream>>>(Ahi, Alo, W1hi, W1lo, b1, N, Hhi, Hlo,
                                                       batch, sumbuf, maxbuf);
    // layer 2
    k_agg<256, false><<<CDIV(N * 64, 256), 256, 0, stream>>>(nullptr, Hhi, Hlo, dis, row_ptr,
                                                             esrc, ecoef, N, Ahi, Alo);
    k_gemm_bf16<256, false><<<ggrid, 256, 0, stream>>>(Ahi, Alo, W2hi, W2lo, b2, N, Hhi, Hlo,
                                                       batch, sumbuf, maxbuf);
    // layer 3 + fused pooling
    k_agg<256, false><<<CDIV(N * 64, 256), 256, 0, stream>>>(nullptr, Hhi, Hlo, dis, row_ptr,
                                                             esrc, ecoef, N, Ahi, Alo);
    k_gemm_bf16<256, true><<<ggrid, 256, 0, stream>>>(Ahi, Alo, W3hi, W3lo, b3, N, Hhi, Hlo,
                                                      batch, sumbuf, maxbuf);

    k_pool_final<<<G, 256, 0, stream>>>(sumbuf, maxbuf, batch, N, gfeat);

    k_mlp<<<G, 512, 512 * 4, stream>>>(gfeat, Wc1, bc1, g1, 512, 512, 1);
    k_mlp<<<G, 256, 512 * 4, stream>>>(g1, Wc2, bc2, g2, 512, 256, 1);
    k_mlp<<<G, 64, 256 * 4, stream>>>(g2, Wc3, bc3, out, 256, 5, 0);
}